// Round 21
// baseline (1059.038 us; speedup 1.0000x reference)
//
#include <hip/hip_runtime.h>
#include <hip/hip_bf16.h>
#include <cstdint>
#include <cstddef>

using bf16 = __hip_bfloat16;
typedef __attribute__((ext_vector_type(8))) short short8;
typedef __attribute__((ext_vector_type(4))) float f32x4;

typedef __attribute__((address_space(1))) const void as1_void;
typedef __attribute__((address_space(3))) void as3_void;

__device__ __forceinline__ f32x4 mfma16x16x32(short8 a, short8 b, f32x4 c) {
  return __builtin_amdgcn_mfma_f32_16x16x32_bf16(a, b, c, 0, 0, 0);
}

__device__ __forceinline__ void gload_lds16(const void* g, void* l) {
  __builtin_amdgcn_global_load_lds((as1_void*)g, (as3_void*)l, 16, 0, 0);
}

__device__ __forceinline__ uint32_t cvtpk(float a, float b) {
  uint32_t r;
  asm("v_cvt_pk_bf16_f32 %0, %1, %2" : "=v"(r) : "v"(a), "v"(b));
  return r;
}

__device__ __forceinline__ float gelu_f(float v) {
  const float u = 0.7978845608f * v * (1.f + 0.044715f * v * v);
  const float e = __expf(-2.f * fabsf(u));
  const float t = (1.f - e) / (1.f + e);
  return 0.5f * v * (1.f + (u < 0.f ? -t : t));
}

// ---------------- problem constants ----------------
static constexpr int MROWS = 39200;
static constexpr int MPAD  = 39424;   // 154 x 256 (256-tile friendly)
static constexpr int TOK2  = 32768;

// ---------------- weight transpose+cast:  in f32 [K][N] -> out bf16 [N][K] ----
__global__ __launch_bounds__(256)
void transpose_cast(const float* __restrict__ in, bf16* __restrict__ out, int K, int N) {
  __shared__ float t[32][33];
  const int tx = threadIdx.x & 31, ty = threadIdx.x >> 5;
  const int bx = blockIdx.x, by = blockIdx.y;
  const int x = bx * 32 + tx;
  for (int r = ty; r < 32; r += 8)
    t[r][tx] = in[(size_t)(by * 32 + r) * N + x];
  __syncthreads();
  const int xo = by * 32 + tx;
  for (int r = ty; r < 32; r += 8)
    out[(size_t)(bx * 32 + r) * K + xo] = __float2bfloat16(t[tx][r]);
}

// ---------------- LN1 + window partition -> bf16 [MPAD][768] ----------------
__global__ __launch_bounds__(256)
void ln1_partition(const float* __restrict__ x, const float* __restrict__ g,
                   const float* __restrict__ bb, bf16* __restrict__ out) {
  const int token = blockIdx.x * 4 + (threadIdx.x >> 6);
  const int lane = threadIdx.x & 63;
  const int win = token / 196, tok = token % 196;
  const int b_ = win / 25, wh = (win / 5) % 5, ww = win % 5;
  const int i = tok / 14, j = tok % 14;
  const int h = wh * 14 + i, w = ww * 14 + j;
  bf16* o = out + (size_t)token * 768;
  if (h >= 64 || w >= 64) {
    for (int t = 0; t < 12; ++t) o[lane + 64 * t] = __float2bfloat16(0.f);
    return;
  }
  const float* src = x + ((size_t)((b_ * 64 + h) * 64 + w)) * 768;
  float vals[12], s = 0.f, ss = 0.f;
  #pragma unroll
  for (int t = 0; t < 12; ++t) {
    float v = src[lane + 64 * t];
    vals[t] = v; s += v; ss += v * v;
  }
  #pragma unroll
  for (int d = 32; d > 0; d >>= 1) { s += __shfl_xor(s, d); ss += __shfl_xor(ss, d); }
  const float mu = s * (1.f / 768.f);
  const float var = ss * (1.f / 768.f) - mu * mu;
  const float inv = rsqrtf(var + 1e-6f);
  #pragma unroll
  for (int t = 0; t < 12; ++t) {
    const int c = lane + 64 * t;
    o[c] = __float2bfloat16((vals[t] - mu) * inv * g[c] + bb[c]);
  }
}

// ---------------- LN2 on x1 (f32, dense [32768][768]) -> bf16 ----------------
__global__ __launch_bounds__(256)
void ln2_kernel(const float* __restrict__ x1, const float* __restrict__ g,
                const float* __restrict__ bb, bf16* __restrict__ out) {
  const int token = blockIdx.x * 4 + (threadIdx.x >> 6);
  const int lane = threadIdx.x & 63;
  const float* src = x1 + (size_t)token * 768;
  bf16* o = out + (size_t)token * 768;
  float vals[12], s = 0.f, ss = 0.f;
  #pragma unroll
  for (int t = 0; t < 12; ++t) {
    float v = src[lane + 64 * t];
    vals[t] = v; s += v; ss += v * v;
  }
  #pragma unroll
  for (int d = 32; d > 0; d >>= 1) { s += __shfl_xor(s, d); ss += __shfl_xor(ss, d); }
  const float mu = s * (1.f / 768.f);
  const float var = ss * (1.f / 768.f) - mu * mu;
  const float inv = rsqrtf(var + 1e-6f);
  #pragma unroll
  for (int t = 0; t < 12; ++t) {
    const int c = lane + 64 * t;
    o[c] = __float2bfloat16((vals[t] - mu) * inv * g[c] + bb[c]);
  }
}

// ---------------- m201-style 8-phase 256x256 GEMM (addr-hoisted, K templated)
// Fragment slot XOR hi^((row>>1)&3) is THREAD-INVARIANT -> reads are
// per-thread base + compile-time immediate. Stage addrs: 4 per-thread
// pointers + scalar koff (koff = kt*ASTRIDE + kh*32; ASTRIDE=64 for
// row-major [M][K], = MPAD*64 for head-major [head][MPAD][64] since
// BK=64 == head width).
template<int MH, bool READB, int VMN>
__device__ __forceinline__ void gphase(
    const char* aR, const char* bR, int aoffB, int boffB,
    f32x4 (&acc)[8][4], short8& b0, short8& b1, short8& b2, short8& b3,
    const bf16* g0, const bf16* g1, char* sdst, int sdoff, int koff, bool doStage) {
  short8 a0 = *(const short8*)(aR + aoffB + (MH * 64 +  0) * 64);
  short8 a1 = *(const short8*)(aR + aoffB + (MH * 64 + 16) * 64);
  short8 a2 = *(const short8*)(aR + aoffB + (MH * 64 + 32) * 64);
  short8 a3 = *(const short8*)(aR + aoffB + (MH * 64 + 48) * 64);
  if constexpr (READB) {
    b0 = *(const short8*)(bR + boffB +  0 * 64);
    b1 = *(const short8*)(bR + boffB + 16 * 64);
    b2 = *(const short8*)(bR + boffB + 32 * 64);
    b3 = *(const short8*)(bR + boffB + 48 * 64);
  }
  if (doStage) {
    gload_lds16(g0 + koff, sdst + sdoff);
    gload_lds16(g1 + koff, sdst + sdoff + 8192);
  }
  __builtin_amdgcn_s_barrier();
  asm volatile("s_waitcnt lgkmcnt(0)" ::: "memory");
  __builtin_amdgcn_sched_barrier(0);
  __builtin_amdgcn_s_setprio(1);
  acc[MH*4+0][0] = mfma16x16x32(a0, b0, acc[MH*4+0][0]);
  acc[MH*4+0][1] = mfma16x16x32(a0, b1, acc[MH*4+0][1]);
  acc[MH*4+0][2] = mfma16x16x32(a0, b2, acc[MH*4+0][2]);
  acc[MH*4+0][3] = mfma16x16x32(a0, b3, acc[MH*4+0][3]);
  acc[MH*4+1][0] = mfma16x16x32(a1, b0, acc[MH*4+1][0]);
  acc[MH*4+1][1] = mfma16x16x32(a1, b1, acc[MH*4+1][1]);
  acc[MH*4+1][2] = mfma16x16x32(a1, b2, acc[MH*4+1][2]);
  acc[MH*4+1][3] = mfma16x16x32(a1, b3, acc[MH*4+1][3]);
  acc[MH*4+2][0] = mfma16x16x32(a2, b0, acc[MH*4+2][0]);
  acc[MH*4+2][1] = mfma16x16x32(a2, b1, acc[MH*4+2][1]);
  acc[MH*4+2][2] = mfma16x16x32(a2, b2, acc[MH*4+2][2]);
  acc[MH*4+2][3] = mfma16x16x32(a2, b3, acc[MH*4+2][3]);
  acc[MH*4+3][0] = mfma16x16x32(a3, b0, acc[MH*4+3][0]);
  acc[MH*4+3][1] = mfma16x16x32(a3, b1, acc[MH*4+3][1]);
  acc[MH*4+3][2] = mfma16x16x32(a3, b2, acc[MH*4+3][2]);
  acc[MH*4+3][3] = mfma16x16x32(a3, b3, acc[MH*4+3][3]);
  __builtin_amdgcn_s_setprio(0);
  if constexpr (VMN == 6) asm volatile("s_waitcnt vmcnt(6)" ::: "memory");
  if constexpr (VMN == 0) asm volatile("s_waitcnt vmcnt(0)" ::: "memory");
  __builtin_amdgcn_s_barrier();
}

// 256x256, BK=64, 8 waves, 8-phase interleave (r16/r20-proven schedule).
// EPI 0: qkv -> q/k/v [head][MPAD][64]; EPI 1: proj (A head-major) + residual;
// EPI 2: gelu -> bf16 [M][3072]; EPI 3: f32 residual. KT compile-time.
template<int EPI, int KT, bool AHEAD>
__global__ __launch_bounds__(512)
void gemm256(const bf16* __restrict__ A, const bf16* __restrict__ Bt,
             const float* __restrict__ bias, int Mreal,
             const float* __restrict__ fin, float* __restrict__ fout,
             bf16* __restrict__ ob0, bf16* __restrict__ ob1, bf16* __restrict__ ob2) {
  __shared__ __align__(16) char SMEM[131072];
  char* const A0k0 = SMEM;
  char* const A0k1 = SMEM + 16384;
  char* const B0k0 = SMEM + 32768;
  char* const B0k1 = SMEM + 49152;
  char* const A1k0 = SMEM + 65536;
  char* const A1k1 = SMEM + 81920;
  char* const B1k0 = SMEM + 98304;
  char* const B1k1 = SMEM + 114688;
  const int tid = threadIdx.x;
  const int lane = tid & 63, wv = tid >> 6;     // wv 0..7
  const int lr = lane & 15, hi = lane >> 4;
  const int wm = wv >> 2, wn = wv & 3;          // 2 x 4 wave grid

  const int gx = gridDim.x;
  const int nwg = gx * gridDim.y;
  int lin = blockIdx.y * gx + blockIdx.x;
  {
    const int q8 = nwg >> 3, r8 = nwg & 7;
    const int xcd = lin & 7, pos = lin >> 3;
    lin = (xcd < r8 ? xcd * (q8 + 1) : r8 * (q8 + 1) + (xcd - r8) * q8) + pos;
  }
  const size_t arow0 = (size_t)(lin / gx) * 256;
  const size_t brow0 = (size_t)(lin % gx) * 256;

  f32x4 acc[8][4] = {};
  short8 b0{}, b1{}, b2{}, b3{};
  constexpr int nt = KT >> 6;              // 12 (K=768) / 48 (K=3072) -- even
  constexpr int ASTRIDE = AHEAD ? (MPAD * 64) : 64;   // per-tile A k-stride

  // per-thread hoisted bases
  const int r0 = tid >> 2;
  const int c0 = (tid & 3) ^ ((r0 >> 1) & 3);
  const bf16* const gA0 = AHEAD ? (A + (arow0 + r0) * 64 + c0 * 8)
                                : (A + (arow0 + r0) * (size_t)KT + c0 * 8);
  const bf16* const gA1 = gA0 + (size_t)128 * (AHEAD ? 64 : KT);
  const bf16* const gB0 = Bt + (brow0 + r0) * (size_t)KT + c0 * 8;
  const bf16* const gB1 = gB0 + (size_t)128 * KT;
  const int sdoff = tid << 4;
  const int cpos  = hi ^ ((lr >> 1) & 3);
  const int aoffB = (wm * 128 + lr) * 64 + (cpos << 4);
  const int boffB = (wn * 64 + lr) * 64 + (cpos << 4);

  auto stageU = [&](bool isB, int kt, int kh, char* dst) {
    if (kt >= nt) return;
    const int koff = isB ? ((kt << 6) + (kh << 5)) : (kt * ASTRIDE + kh * 32);
    gload_lds16((isB ? gB0 : gA0) + koff, dst + sdoff);
    gload_lds16((isB ? gB1 : gA1) + koff, dst + sdoff + 8192);
  };

  // prologue (FIFO order = ledger order): tile0's 4 units, tile1's first 3
  stageU(true,  0, 0, B0k0);
  stageU(false, 0, 0, A0k0);
  stageU(true,  0, 1, B0k1);
  stageU(false, 0, 1, A0k1);
  stageU(true,  1, 0, B1k0);
  stageU(false, 1, 0, A1k0);
  stageU(true,  1, 1, B1k1);
  asm volatile("s_waitcnt vmcnt(6)" ::: "memory");   // tile0 fully landed
  __builtin_amdgcn_s_barrier();

  constexpr int niter = nt >> 1;
  for (int it = 0; it < niter - 1; ++it) {
    const int t = it * 2;
    const int kfa1  = (t + 1) * ASTRIDE + 32;
    const int kfa20 = (t + 2) * ASTRIDE, kfa21 = kfa20 + 32;
    const int kfa30 = (t + 3) * ASTRIDE;
    const int kfb20 = (t + 2) << 6, kfb21 = kfb20 + 32;
    const int kfb30 = (t + 3) << 6, kfb31 = kfb30 + 32;
    gphase<0,true ,-1>(A0k0, B0k0, aoffB, boffB, acc, b0,b1,b2,b3, gA0, gA1, A1k1, sdoff, kfa1,  true);
    gphase<1,false,-1>(A0k0, B0k0, aoffB, boffB, acc, b0,b1,b2,b3, gB0, gB1, B0k0, sdoff, kfb20, true);
    gphase<0,true ,-1>(A0k1, B0k1, aoffB, boffB, acc, b0,b1,b2,b3, gA0, gA1, A0k0, sdoff, kfa20, true);
    gphase<1,false, 6>(A0k1, B0k1, aoffB, boffB, acc, b0,b1,b2,b3, gB0, gB1, B0k1, sdoff, kfb21, true);
    gphase<0,true ,-1>(A1k0, B1k0, aoffB, boffB, acc, b0,b1,b2,b3, gA0, gA1, A0k1, sdoff, kfa21, true);
    gphase<1,false,-1>(A1k0, B1k0, aoffB, boffB, acc, b0,b1,b2,b3, gB0, gB1, B1k0, sdoff, kfb30, true);
    gphase<0,true ,-1>(A1k1, B1k1, aoffB, boffB, acc, b0,b1,b2,b3, gA0, gA1, A1k0, sdoff, kfa30, true);
    gphase<1,false, 6>(A1k1, B1k1, aoffB, boffB, acc, b0,b1,b2,b3, gB0, gB1, B1k1, sdoff, kfb31, true);
  }
  {  // final iteration: tiles nt-2, nt-1; out-of-range stages skipped; drain
    const int t = nt - 2;
    const int kfa1 = (t + 1) * ASTRIDE + 32;
    gphase<0,true ,-1>(A0k0, B0k0, aoffB, boffB, acc, b0,b1,b2,b3, gA0, gA1, A1k1, sdoff, kfa1, true);
    gphase<1,false,-1>(A0k0, B0k0, aoffB, boffB, acc, b0,b1,b2,b3, gB0, gB1, B0k0, sdoff, 0, false);
    gphase<0,true ,-1>(A0k1, B0k1, aoffB, boffB, acc, b0,b1,b2,b3, gA0, gA1, A0k0, sdoff, 0, false);
    gphase<1,false, 0>(A0k1, B0k1, aoffB, boffB, acc, b0,b1,b2,b3, gB0, gB1, B0k1, sdoff, 0, false);
    gphase<0,true ,-1>(A1k0, B1k0, aoffB, boffB, acc, b0,b1,b2,b3, gA0, gA1, A0k1, sdoff, 0, false);
    gphase<1,false,-1>(A1k0, B1k0, aoffB, boffB, acc, b0,b1,b2,b3, gB0, gB1, B1k0, sdoff, 0, false);
    gphase<0,true ,-1>(A1k1, B1k1, aoffB, boffB, acc, b0,b1,b2,b3, gA0, gA1, A1k0, sdoff, 0, false);
    gphase<1,false, 0>(A1k1, B1k1, aoffB, boffB, acc, b0,b1,b2,b3, gB0, gB1, B1k1, sdoff, 0, false);
  }

  if constexpr (EPI == 0) {
    // ---- qkv: wave-local LDS-staged bf16 drain to q/k/v [head][MPAD][64] ----
    __syncthreads();
    char* ep = SMEM + wv * 16384;              // [128 rows][64 cols bf16]
    #pragma unroll
    for (int m = 0; m < 8; ++m) {
      #pragma unroll
      for (int n = 0; n < 4; ++n) {
        const int col = n * 16 + lr;
        const float bv = bias[(int)brow0 + wn * 64 + col];
        #pragma unroll
        for (int e = 0; e < 4; ++e) {
          const int row_l = m * 16 + hi * 4 + e;
          const int byte = row_l * 128 + col * 2;
          *(bf16*)(ep + (byte ^ ((row_l & 7) << 4))) = __float2bfloat16(acc[m][n][e] + bv);
        }
      }
    }
    __syncthreads();
    // wave's 64-col span = one head-d chunk: which/head constant per wave
    const int hchunk = ((int)brow0 + wn * 64) >> 6;      // 0..35
    const int which = hchunk / 12, head = hchunk % 12;
    bf16* dstb = (which == 0) ? ob0 : ((which == 1) ? ob1 : ob2);
    #pragma unroll
    for (int u = 0; u < 16; ++u) {
      const int unit = u * 64 + lane;          // 1024 units of 16 B per wave
      const int row_l = unit >> 3, slot = unit & 7;
      const int byte = row_l * 128 + slot * 16;
      const short8 val = *(const short8*)(ep + (byte ^ ((row_l & 7) << 4)));
      const int grow = (int)arow0 + wm * 128 + row_l;
      if (grow < Mreal)
        *(short8*)&dstb[((size_t)head * MPAD + grow) * 64 + slot * 8] = val;
    }
  } else if constexpr (EPI == 1) {
    // ---- proj: f32 residual + window unpartition scatter ----
    #pragma unroll
    for (int n = 0; n < 4; ++n) {
      const int col = (int)brow0 + wn * 64 + n * 16 + lr;
      const float bv = bias[col];
      #pragma unroll
      for (int m = 0; m < 8; ++m) {
        #pragma unroll
        for (int e = 0; e < 4; ++e) {
          const int row = (int)arow0 + wm * 128 + m * 16 + hi * 4 + e;
          const float v = acc[m][n][e] + bv;
          if (row < Mreal) {
            const int win = row / 196, tok = row % 196;
            const int b_ = win / 25, wh = (win / 5) % 5, ww = win % 5;
            const int i = tok / 14, j = tok % 14;
            const int h = wh * 14 + i, w = ww * 14 + j;
            if (h < 64 && w < 64) {
              const size_t idx = ((size_t)((b_ * 64 + h) * 64 + w)) * 768 + col;
              fout[idx] = fin[idx] + v;
            }
          }
        }
      }
    }
  } else if constexpr (EPI == 2) {
    // ---- gelu + LDS-staged coalesced bf16 stores (wave-local 8 KB region) ----
    char* ep = SMEM + wv * 8192;               // [64 rows][64 cols bf16]
    #pragma unroll
    for (int h = 0; h < 2; ++h) {
      #pragma unroll
      for (int m2 = 0; m2 < 4; ++m2) {
        #pragma unroll
        for (int n = 0; n < 4; ++n) {
          const int col = n * 16 + lr;
          const float bv = bias[(int)brow0 + wn * 64 + col];
          #pragma unroll
          for (int e = 0; e < 4; ++e) {
            const int row_l = m2 * 16 + hi * 4 + e;
            const float v = gelu_f(acc[h * 4 + m2][n][e] + bv);
            *(bf16*)(ep + row_l * 128 + (((col >> 3) ^ (row_l & 7)) << 4) + ((col & 7) << 1))
                = __float2bfloat16(v);
          }
        }
      }
      #pragma unroll
      for (int p = 0; p < 8; ++p) {
        const int row_l = p * 8 + (lane >> 3);
        const int slot  = lane & 7;
        const short8 val = *(const short8*)(ep + row_l * 128 + ((slot ^ (row_l & 7)) << 4));
        const size_t grow = arow0 + wm * 128 + h * 64 + row_l;
        const int gcol = (int)brow0 + wn * 64 + slot * 8;
        *(short8*)&ob0[grow * 3072 + gcol] = val;
      }
    }
  } else {
    // ---- EPI 3: dense f32 residual ----
    #pragma unroll
    for (int n = 0; n < 4; ++n) {
      const int col = (int)brow0 + wn * 64 + n * 16 + lr;
      const float bv = bias[col];
      #pragma unroll
      for (int m = 0; m < 8; ++m) {
        #pragma unroll
        for (int e = 0; e < 4; ++e) {
          const size_t row = arow0 + wm * 128 + m * 16 + hi * 4 + e;
          const size_t idx = row * 768 + col;
          fout[idx] = fin[idx] + acc[m][n][e] + bv;
        }
      }
    }
  }
}

// ---------------- fused window attention (r12-proven, untouched) -------------
__global__ __launch_bounds__(512, 2)
void attn_kernel(const bf16* __restrict__ qb, const bf16* __restrict__ kb,
                 const bf16* __restrict__ vb, const float* __restrict__ rph,
                 const float* __restrict__ rpw, bf16* __restrict__ aout) {
  __shared__ __align__(16) char SM[65248];
  bf16* pbh    = (bf16*)SM;
  bf16* pbw    = (bf16*)(SM + 4096);
  bf16* Gh     = (bf16*)(SM + 8192);
  bf16* Gw     = (bf16*)(SM + 23168);
  char* klds   = SM;                    // [200 rows][128 B], XOR-swizzled
  char* vtb    = SM + 25600;            // [64 d][448 B], XOR-swizzled
  bf16* relh_s = (bf16*)(SM + 54272);   // [196][14]
  bf16* relw_s = (bf16*)(SM + 59760);   // [196][14]

  const int bh = blockIdx.x;             // 0..2399
  const int win = bh / 12, head = bh % 12;
  const size_t base = ((size_t)head * MPAD + win * 196) * 64;
  const bf16* Q  = qb + base;
  const bf16* Kp = kb + base;
  const bf16* Vp = vb + base;
  const int tid = threadIdx.x, lane = tid & 63, wv = tid >> 6;   // wv 0..7
  const int lr = lane & 15, hi = lane >> 4;

  for (int i = tid; i < 32 * 64; i += 512) {
    const int r = i >> 6, c = i & 63;
    const bool ok = r < 27;
    pbh[i] = __float2bfloat16(ok ? rph[r * 64 + c] : 0.f);
    pbw[i] = __float2bfloat16(ok ? rpw[r * 64 + c] : 0.f);
  }
  __syncthreads();
  {
    short8 bh00 = *(const short8*)&pbh[(lr) * 64 + hi * 8];
    short8 bh01 = *(const short8*)&pbh[(lr) * 64 + 32 + hi * 8];
    short8 bh10 = *(const short8*)&pbh[(16 + lr) * 64 + hi * 8];
    short8 bh11 = *(const short8*)&pbh[(16 + lr) * 64 + 32 + hi * 8];
    short8 bw00 = *(const short8*)&pbw[(lr) * 64 + hi * 8];
    short8 bw01 = *(const short8*)&pbw[(lr) * 64 + 32 + hi * 8];
    short8 bw10 = *(const short8*)&pbw[(16 + lr) * 64 + hi * 8];
    short8 bw11 = *(const short8*)&pbw[(16 + lr) * 64 + 32 + hi * 8];
    for (int mt = wv; mt < 13; mt += 8) {
      const short8 a0 = *(const short8*)&Q[(mt * 16 + lr) * 64 + hi * 8];
      const short8 a1 = *(const short8*)&Q[(mt * 16 + lr) * 64 + 32 + hi * 8];
      f32x4 g0 = {}, g1 = {}, g2 = {}, g3 = {};
      g0 = mfma16x16x32(a0, bh00, g0); g0 = mfma16x16x32(a1, bh01, g0);
      g1 = mfma16x16x32(a0, bh10, g1); g1 = mfma16x16x32(a1, bh11, g1);
      g2 = mfma16x16x32(a0, bw00, g2); g2 = mfma16x16x32(a1, bw01, g2);
      g3 = mfma16x16x32(a0, bw10, g3); g3 = mfma16x16x32(a1, bw11, g3);
      #pragma unroll
      for (int e = 0; e < 4; ++e) {
        const int row = mt * 16 + hi * 4 + e;
        Gh[row * 36 + lr]      = __float2bfloat16(g0[e]);
        Gh[row * 36 + 16 + lr] = __float2bfloat16(g1[e]);
        Gw[row * 36 + lr]      = __float2bfloat16(g2[e]);
        Gw[row * 36 + 16 + lr] = __float2bfloat16(g3[e]);
      }
    }
  }
  __syncthreads();
  bf16 ghr[6], gwr[6];
  #pragma unroll
  for (int t = 0; t < 6; ++t) {
    const int i = tid + t * 512;
    if (i < 196 * 14) {
      const int q = i / 14, kk = i - (i / 14) * 14;
      const int rh = q / 14 - kk + 13;
      const int rw2 = q - (q / 14) * 14 - kk + 13;
      ghr[t] = Gh[q * 36 + rh];
      gwr[t] = Gw[q * 36 + rw2];
    }
  }
  __syncthreads();
  #pragma unroll
  for (int t = 0; t < 6; ++t) {
    const int i = tid + t * 512;
    if (i < 196 * 14) { relh_s[i] = ghr[t]; relw_s[i] = gwr[t]; }
  }
  for (int c = wv; c < 25; c += 8) {
    const int row = c * 8 + (lane >> 3);
    const int ch  = (lane & 7) ^ (row & 7);
    gload_lds16(Kp + row * 64 + ch * 8, klds + c * 1024);
  }
  for (int i = tid; i < 196 * 8; i += 512) {
    const int key = i >> 3, dg = (i & 7) * 8;
    const short8 v = *(const short8*)&Vp[key * 64 + dg];
    #pragma unroll
    for (int j = 0; j < 8; ++j) {
      const int idx = (dg + j) * 448 + key * 2;
      *(bf16*)(vtb + (idx ^ (j << 4))) = ((const bf16*)&v)[j];
    }
  }
  for (int i = tid; i < 64 * 28; i += 512) {
    const int d = i / 28, key = 196 + i - (i / 28) * 28;
    const int idx = d * 448 + key * 2;
    *(bf16*)(vtb + (idx ^ ((d & 7) << 4))) = __float2bfloat16(0.f);
  }
  __syncthreads();

  for (int qt = wv; qt < 13; qt += 8) {
    const int q = qt * 16 + lr;
    const int qc = q < 196 ? q : 195;
    const short8 bq0 = *(const short8*)&Q[(qt * 16 + lr) * 64 + hi * 8];
    const short8 bq1 = *(const short8*)&Q[(qt * 16 + lr) * 64 + 32 + hi * 8];
    f32x4 s[13];
    __builtin_amdgcn_s_setprio(1);
    #pragma unroll
    for (int nt = 0; nt < 13; ++nt) {
      const int key = nt * 16 + lr;
      const char* kr = klds + key * 128;
      const short8 ka0 = *(const short8*)(kr + (((hi) ^ (key & 7)) << 4));
      const short8 ka1 = *(const short8*)(kr + (((hi + 4) ^ (key & 7)) << 4));
      f32x4 z = {};
      z = mfma16x16x32(ka0, bq0, z);
      z = mfma16x16x32(ka1, bq1, z);
      s[nt] = z;
    }
    __builtin_amdgcn_s_setprio(0);
    float mx = -3.0e38f;
    #pragma unroll
    for (int nt = 0; nt < 13; ++nt) {
      #pragma unroll
      for (int e = 0; e < 4; ++e) {
        const int key = nt * 16 + hi * 4 + e;
        const int kh = key / 14, kw = key - kh * 14;
        float v = s[nt][e] * 0.125f + __bfloat162float(relh_s[qc * 14 + kh])
                                    + __bfloat162float(relw_s[qc * 14 + kw]);
        v = (key < 196) ? v : -3.0e38f;
        s[nt][e] = v;
        mx = fmaxf(mx, v);
      }
    }
    mx = fmaxf(mx, __shfl_xor(mx, 16));
    mx = fmaxf(mx, __shfl_xor(mx, 32));
    float sm = 0.f;
    uint32_t pk0[14], pk1[14];
    #pragma unroll
    for (int nt = 0; nt < 13; ++nt) {
      const float p0 = __expf(s[nt][0] - mx);
      const float p1 = __expf(s[nt][1] - mx);
      const float p2 = __expf(s[nt][2] - mx);
      const float p3 = __expf(s[nt][3] - mx);
      sm += (p0 + p1) + (p2 + p3);
      pk0[nt] = cvtpk(p0, p1);
      pk1[nt] = cvtpk(p2, p3);
    }
    pk0[13] = 0u; pk1[13] = 0u;
    sm += __shfl_xor(sm, 16);
    sm += __shfl_xor(sm, 32);
    const float rinv = 1.f / sm;
    f32x4 o[4] = {};
    #pragma unroll
    for (int kk = 0; kk < 7; ++kk) {
      const uint32_t x0 = pk0[2 * kk],     x1 = pk1[2 * kk];
      const uint32_t y0 = pk0[2 * kk + 1], y1 = pk1[2 * kk + 1];
      const uint32_t s0 = (hi < 2) ? y0 : x0, s1 = (hi < 2) ? y1 : x1;
      const uint32_t t0 = __shfl_xor(s0, 32), t1 = __shfl_xor(s1, 32);
      const uint32_t o0 = (hi < 2) ? x0 : y0, o1 = (hi < 2) ? x1 : y1;
      const bool sendOwn = (hi == 1) || (hi == 2);
      const uint32_t u0 = sendOwn ? o0 : t0, u1 = sendOwn ? o1 : t1;
      const uint32_t r0 = __shfl_xor(u0, 16), r1 = __shfl_xor(u1, 16);
      union { uint32_t u[4]; short8 v; } pf;
      pf.u[0] = (hi == 0) ? x0 : ((hi == 2) ? t0 : r0);
      pf.u[1] = (hi == 0) ? x1 : ((hi == 2) ? t1 : r1);
      pf.u[2] = (hi == 3) ? y0 : ((hi == 1) ? t0 : r0);
      pf.u[3] = (hi == 3) ? y1 : ((hi == 1) ? t1 : r1);
      __builtin_amdgcn_s_setprio(1);
      #pragma unroll
      for (int n2 = 0; n2 < 4; ++n2) {
        const int d = n2 * 16 + lr;
        const int idx = d * 448 + (kk * 32 + hi * 8) * 2;
        const short8 va = *(const short8*)(vtb + (idx ^ ((lr & 7) << 4)));
        o[n2] = mfma16x16x32(va, pf.v, o[n2]);
      }
      __builtin_amdgcn_s_setprio(0);
    }
    if (q < 196) {
      bf16* orow = aout + ((size_t)head * MPAD + win * 196 + q) * 64;
      #pragma unroll
      for (int n2 = 0; n2 < 4; ++n2) {
        uint32_t d0 = cvtpk(o[n2][0] * rinv, o[n2][1] * rinv);
        uint32_t d1 = cvtpk(o[n2][2] * rinv, o[n2][3] * rinv);
        uint32_t* dst = (uint32_t*)&orow[n2 * 16 + hi * 4];
        dst[0] = d0; dst[1] = d1;
      }
    }
  }
}

// ---------------- host ----------------
extern "C" void kernel_launch(void* const* d_in, const int* in_sizes, int n_in,
                              void* d_out, int out_size, void* d_ws, size_t ws_size,
                              hipStream_t stream) {
  (void)in_sizes; (void)n_in; (void)out_size; (void)ws_size;
  const float* x      = (const float*)d_in[0];
  const float* ln1_g  = (const float*)d_in[1];
  const float* ln1_b  = (const float*)d_in[2];
  const float* qkv_w  = (const float*)d_in[3];
  const float* qkv_b  = (const float*)d_in[4];
  const float* proj_w = (const float*)d_in[5];
  const float* proj_b = (const float*)d_in[6];
  const float* rph    = (const float*)d_in[7];
  const float* rpw    = (const float*)d_in[8];
  const float* ln2_g  = (const float*)d_in[9];
  const float* ln2_b  = (const float*)d_in[10];
  const float* w1     = (const float*)d_in[11];
  const float* b1v    = (const float*)d_in[12];
  const float* w2     = (const float*)d_in[13];
  const float* b2v    = (const float*)d_in[14];
  float* outp = (float*)d_out;   // also serves as x1 (written by proj epilogue)

  char* ws = (char*)d_ws;
  size_t off = 0;
  auto alloc = [&](size_t bytes) { char* p = ws + off; off += (bytes + 255) & ~(size_t)255; return p; };
  bf16* qkv_wt  = (bf16*)alloc((size_t)2304 * 768 * 2);
  bf16* proj_wt = (bf16*)alloc((size_t)768 * 768 * 2);
  bf16* w1t     = (bf16*)alloc((size_t)3072 * 768 * 2);
  bf16* w2t     = (bf16*)alloc((size_t)768 * 3072 * 2);
  const size_t szB1 = (size_t)MPAD * 768 * 2;
  const size_t szB2 = (size_t)TOK2 * 768 * 2;
  char* regB = alloc(szB1 > szB2 ? szB1 : szB2);
  const size_t szQKV = (size_t)3 * 12 * MPAD * 64 * 2;
  const size_t szH   = (size_t)TOK2 * 3072 * 2;
  char* regC = alloc(szQKV > szH ? szQKV : szH);

  bf16* xnwin   = (bf16*)regB;
  bf16* attnout = (bf16*)regB;
  bf16* xn2     = (bf16*)regB;
  bf16* qbuf    = (bf16*)regC;                       // [12][MPAD][64]
  bf16* kbuf    = qbuf + (size_t)12 * MPAD * 64;
  bf16* vbuf    = kbuf + (size_t)12 * MPAD * 64;
  bf16* hbuf    = (bf16*)regC;

  transpose_cast<<<dim3(2304 / 32, 768 / 32), 256, 0, stream>>>(qkv_w, qkv_wt, 768, 2304);
  transpose_cast<<<dim3(768 / 32, 768 / 32), 256, 0, stream>>>(proj_w, proj_wt, 768, 768);
  transpose_cast<<<dim3(3072 / 32, 768 / 32), 256, 0, stream>>>(w1, w1t, 768, 3072);
  transpose_cast<<<dim3(768 / 32, 3072 / 32), 256, 0, stream>>>(w2, w2t, 3072, 768);

  ln1_partition<<<dim3(MROWS / 4), 256, 0, stream>>>(x, ln1_g, ln1_b, xnwin);

  // qkv on the 8-phase 256^2 kernel (M padded to 39424)
  gemm256<0, 768, false><<<dim3(2304 / 256, MPAD / 256), 512, 0, stream>>>(
      xnwin, qkv_wt, qkv_b, MROWS, nullptr, nullptr, qbuf, kbuf, vbuf);

  attn_kernel<<<dim3(2400), 512, 0, stream>>>(qbuf, kbuf, vbuf, rph, rpw, attnout);

  // proj on the 8-phase 256^2 kernel (A head-major; BK=64 == head width)
  gemm256<1, 768, true><<<dim3(768 / 256, MPAD / 256), 512, 0, stream>>>(
      attnout, proj_wt, proj_b, MROWS, x, outp, nullptr, nullptr, nullptr);

  ln2_kernel<<<dim3(TOK2 / 4), 256, 0, stream>>>(outp, ln2_g, ln2_b, xn2);

  // MLP on the 8-phase 256^2 kernel
  gemm256<2, 768, false><<<dim3(3072 / 256, TOK2 / 256), 512, 0, stream>>>(
      xn2, w1t, b1v, TOK2, nullptr, nullptr, hbuf, nullptr, nullptr);
  gemm256<3, 3072, false><<<dim3(768 / 256, TOK2 / 256), 512, 0, stream>>>(
      hbuf, w2t, b2v, TOK2, outp, outp, nullptr, nullptr, nullptr);
}

// Round 22
// 1042.038 us; speedup vs baseline: 1.0163x; 1.0163x over previous
//
#include <hip/hip_runtime.h>
#include <hip/hip_bf16.h>
#include <cstdint>
#include <cstddef>

using bf16 = __hip_bfloat16;
typedef __attribute__((ext_vector_type(8))) short short8;
typedef __attribute__((ext_vector_type(4))) float f32x4;

typedef __attribute__((address_space(1))) const void as1_void;
typedef __attribute__((address_space(3))) void as3_void;

__device__ __forceinline__ f32x4 mfma16x16x32(short8 a, short8 b, f32x4 c) {
  return __builtin_amdgcn_mfma_f32_16x16x32_bf16(a, b, c, 0, 0, 0);
}

__device__ __forceinline__ void gload_lds16(const void* g, void* l) {
  __builtin_amdgcn_global_load_lds((as1_void*)g, (as3_void*)l, 16, 0, 0);
}

__device__ __forceinline__ uint32_t cvtpk(float a, float b) {
  uint32_t r;
  asm("v_cvt_pk_bf16_f32 %0, %1, %2" : "=v"(r) : "v"(a), "v"(b));
  return r;
}

__device__ __forceinline__ float gelu_f(float v) {
  const float u = 0.7978845608f * v * (1.f + 0.044715f * v * v);
  const float e = __expf(-2.f * fabsf(u));
  const float t = (1.f - e) / (1.f + e);
  return 0.5f * v * (1.f + (u < 0.f ? -t : t));
}

// ---------------- problem constants ----------------
static constexpr int MROWS = 39200;
static constexpr int MPAD  = 39424;   // 154 x 256 (256-tile friendly)
static constexpr int TOK2  = 32768;

// ---------------- weight transpose+cast:  in f32 [K][N] -> out bf16 [N][K] ----
__global__ __launch_bounds__(256)
void transpose_cast(const float* __restrict__ in, bf16* __restrict__ out, int K, int N) {
  __shared__ float t[32][33];
  const int tx = threadIdx.x & 31, ty = threadIdx.x >> 5;
  const int bx = blockIdx.x, by = blockIdx.y;
  const int x = bx * 32 + tx;
  for (int r = ty; r < 32; r += 8)
    t[r][tx] = in[(size_t)(by * 32 + r) * N + x];
  __syncthreads();
  const int xo = by * 32 + tx;
  for (int r = ty; r < 32; r += 8)
    out[(size_t)(bx * 32 + r) * K + xo] = __float2bfloat16(t[tx][r]);
}

// ---------------- LN1 + window partition -> bf16 [MPAD][768] ----------------
__global__ __launch_bounds__(256)
void ln1_partition(const float* __restrict__ x, const float* __restrict__ g,
                   const float* __restrict__ bb, bf16* __restrict__ out) {
  const int token = blockIdx.x * 4 + (threadIdx.x >> 6);
  const int lane = threadIdx.x & 63;
  const int win = token / 196, tok = token % 196;
  const int b_ = win / 25, wh = (win / 5) % 5, ww = win % 5;
  const int i = tok / 14, j = tok % 14;
  const int h = wh * 14 + i, w = ww * 14 + j;
  bf16* o = out + (size_t)token * 768;
  if (h >= 64 || w >= 64) {
    for (int t = 0; t < 12; ++t) o[lane + 64 * t] = __float2bfloat16(0.f);
    return;
  }
  const float* src = x + ((size_t)((b_ * 64 + h) * 64 + w)) * 768;
  float vals[12], s = 0.f, ss = 0.f;
  #pragma unroll
  for (int t = 0; t < 12; ++t) {
    float v = src[lane + 64 * t];
    vals[t] = v; s += v; ss += v * v;
  }
  #pragma unroll
  for (int d = 32; d > 0; d >>= 1) { s += __shfl_xor(s, d); ss += __shfl_xor(ss, d); }
  const float mu = s * (1.f / 768.f);
  const float var = ss * (1.f / 768.f) - mu * mu;
  const float inv = rsqrtf(var + 1e-6f);
  #pragma unroll
  for (int t = 0; t < 12; ++t) {
    const int c = lane + 64 * t;
    o[c] = __float2bfloat16((vals[t] - mu) * inv * g[c] + bb[c]);
  }
}

// ---------------- LN2 on x1 (f32, dense [32768][768]) -> bf16 ----------------
__global__ __launch_bounds__(256)
void ln2_kernel(const float* __restrict__ x1, const float* __restrict__ g,
                const float* __restrict__ bb, bf16* __restrict__ out) {
  const int token = blockIdx.x * 4 + (threadIdx.x >> 6);
  const int lane = threadIdx.x & 63;
  const float* src = x1 + (size_t)token * 768;
  bf16* o = out + (size_t)token * 768;
  float vals[12], s = 0.f, ss = 0.f;
  #pragma unroll
  for (int t = 0; t < 12; ++t) {
    float v = src[lane + 64 * t];
    vals[t] = v; s += v; ss += v * v;
  }
  #pragma unroll
  for (int d = 32; d > 0; d >>= 1) { s += __shfl_xor(s, d); ss += __shfl_xor(ss, d); }
  const float mu = s * (1.f / 768.f);
  const float var = ss * (1.f / 768.f) - mu * mu;
  const float inv = rsqrtf(var + 1e-6f);
  #pragma unroll
  for (int t = 0; t < 12; ++t) {
    const int c = lane + 64 * t;
    o[c] = __float2bfloat16((vals[t] - mu) * inv * g[c] + bb[c]);
  }
}

// ---------------- 128x128 GEMM (proj only; r5/r6-proven) ------------
template<int EPI>
__global__ __launch_bounds__(256)
void gemm_bf16(const bf16* __restrict__ A, const bf16* __restrict__ Bt,
               const float* __restrict__ bias, int K, int Mreal,
               const float* __restrict__ fin, float* __restrict__ fout,
               bf16* __restrict__ ob0, bf16* __restrict__ ob1, bf16* __restrict__ ob2) {
  __shared__ __align__(16) bf16 SMEM[16384];                 // 32 KB
  bf16* const lA0 = SMEM;
  bf16* const lA1 = SMEM + 4096;
  bf16* const lB0 = SMEM + 8192;
  bf16* const lB1 = SMEM + 12288;
  const int tid = threadIdx.x;
  const int lane = tid & 63, wv = tid >> 6;
  const int lr = lane & 15, hi = lane >> 4;
  const int wm = wv >> 1, wn = wv & 1;

  const int gx = gridDim.x;
  const int nwg = gx * gridDim.y;
  int lin = blockIdx.y * gx + blockIdx.x;
  {
    const int q8 = nwg >> 3, r8 = nwg & 7;
    const int xcd = lin & 7, pos = lin >> 3;
    lin = (xcd < r8 ? xcd * (q8 + 1) : r8 * (q8 + 1) + (xcd - r8) * q8) + pos;
  }
  const size_t arow0 = (size_t)(lin / gx) * 128;
  const size_t brow0 = (size_t)(lin % gx) * 128;
  f32x4 acc[4][4] = {};

  auto stage = [&](bf16* bufA, bf16* bufB, int kt) {
    const int k0 = kt * 32;
    #pragma unroll
    for (int it = 0; it < 2; ++it) {
      const int seg = it * 256 + tid;
      const int row = seg >> 2, kq = seg & 3;
      const size_t dst = (size_t)(it * 256 + wv * 64) * 8;
      if constexpr (EPI == 1) {
        const int k = k0 + kq * 8;   // A layout: [head][MPAD][64]
        gload_lds16(A + ((size_t)(k >> 6) * MPAD + arow0 + row) * 64 + (k & 63), bufA + dst);
      } else {
        gload_lds16(A + (arow0 + row) * K + k0 + kq * 8, bufA + dst);
      }
      gload_lds16(Bt + (brow0 + row) * K + k0 + kq * 8, bufB + dst);
    }
  };
  auto compute = [&](const bf16* bufA, const bf16* bufB) {
    short8 af[4], bfr[4];
    #pragma unroll
    for (int m = 0; m < 4; ++m) af[m] = *(const short8*)&bufA[(wm * 64 + m * 16 + lr) * 32 + hi * 8];
    #pragma unroll
    for (int n = 0; n < 4; ++n) bfr[n] = *(const short8*)&bufB[(wn * 64 + n * 16 + lr) * 32 + hi * 8];
    #pragma unroll
    for (int m = 0; m < 4; ++m)
      #pragma unroll
      for (int n = 0; n < 4; ++n)
        acc[m][n] = mfma16x16x32(af[m], bfr[n], acc[m][n]);
  };

  const int nt = K >> 5;               // even
  stage(lA0, lB0, 0);
  __syncthreads();
  for (int t = 0; t < nt; t += 2) {
    if (t + 1 < nt) stage(lA1, lB1, t + 1);
    compute(lA0, lB0);
    __syncthreads();
    if (t + 2 < nt) stage(lA0, lB0, t + 2);
    compute(lA1, lB1);
    __syncthreads();
  }

  // ---- EPI 1: proj residual (f32 scatter) ----
  #pragma unroll
  for (int n = 0; n < 4; ++n) {
    const int col = (int)brow0 + wn * 64 + n * 16 + lr;
    const float bv = bias[col];
    #pragma unroll
    for (int m = 0; m < 4; ++m) {
      #pragma unroll
      for (int e = 0; e < 4; ++e) {
        const int row = (int)arow0 + wm * 64 + m * 16 + hi * 4 + e;
        const float v = acc[m][n][e] + bv;
        if (row < Mreal) {
          const int win = row / 196, tok = row % 196;
          const int b_ = win / 25, wh = (win / 5) % 5, ww = win % 5;
          const int i = tok / 14, j = tok % 14;
          const int h = wh * 14 + i, w = ww * 14 + j;
          if (h < 64 && w < 64) {
            const size_t idx = ((size_t)((b_ * 64 + h) * 64 + w)) * 768 + col;
            fout[idx] = fin[idx] + v;
          }
        }
      }
    }
  }
}

// ---------------- m201-style 8-phase 256x256 GEMM (addr-hoisted, K templated)
// Fragment slot XOR hi^((row>>1)&3) is THREAD-INVARIANT (row bits 1-2 come
// only from lr) -> reads are per-thread base + compile-time immediate.
// Stage global addrs are 4 precomputed per-thread pointers + scalar koff.
template<int MH, bool READB, int VMN>
__device__ __forceinline__ void gphase(
    const char* aR, const char* bR, int aoffB, int boffB,
    f32x4 (&acc)[8][4], short8& b0, short8& b1, short8& b2, short8& b3,
    const bf16* g0, const bf16* g1, char* sdst, int sdoff, int koff, bool doStage) {
  short8 a0 = *(const short8*)(aR + aoffB + (MH * 64 +  0) * 64);
  short8 a1 = *(const short8*)(aR + aoffB + (MH * 64 + 16) * 64);
  short8 a2 = *(const short8*)(aR + aoffB + (MH * 64 + 32) * 64);
  short8 a3 = *(const short8*)(aR + aoffB + (MH * 64 + 48) * 64);
  if constexpr (READB) {
    b0 = *(const short8*)(bR + boffB +  0 * 64);
    b1 = *(const short8*)(bR + boffB + 16 * 64);
    b2 = *(const short8*)(bR + boffB + 32 * 64);
    b3 = *(const short8*)(bR + boffB + 48 * 64);
  }
  if (doStage) {
    gload_lds16(g0 + koff, sdst + sdoff);
    gload_lds16(g1 + koff, sdst + sdoff + 8192);
  }
  __builtin_amdgcn_s_barrier();
  asm volatile("s_waitcnt lgkmcnt(0)" ::: "memory");
  __builtin_amdgcn_sched_barrier(0);
  __builtin_amdgcn_s_setprio(1);
  acc[MH*4+0][0] = mfma16x16x32(a0, b0, acc[MH*4+0][0]);
  acc[MH*4+0][1] = mfma16x16x32(a0, b1, acc[MH*4+0][1]);
  acc[MH*4+0][2] = mfma16x16x32(a0, b2, acc[MH*4+0][2]);
  acc[MH*4+0][3] = mfma16x16x32(a0, b3, acc[MH*4+0][3]);
  acc[MH*4+1][0] = mfma16x16x32(a1, b0, acc[MH*4+1][0]);
  acc[MH*4+1][1] = mfma16x16x32(a1, b1, acc[MH*4+1][1]);
  acc[MH*4+1][2] = mfma16x16x32(a1, b2, acc[MH*4+1][2]);
  acc[MH*4+1][3] = mfma16x16x32(a1, b3, acc[MH*4+1][3]);
  acc[MH*4+2][0] = mfma16x16x32(a2, b0, acc[MH*4+2][0]);
  acc[MH*4+2][1] = mfma16x16x32(a2, b1, acc[MH*4+2][1]);
  acc[MH*4+2][2] = mfma16x16x32(a2, b2, acc[MH*4+2][2]);
  acc[MH*4+2][3] = mfma16x16x32(a2, b3, acc[MH*4+2][3]);
  acc[MH*4+3][0] = mfma16x16x32(a3, b0, acc[MH*4+3][0]);
  acc[MH*4+3][1] = mfma16x16x32(a3, b1, acc[MH*4+3][1]);
  acc[MH*4+3][2] = mfma16x16x32(a3, b2, acc[MH*4+3][2]);
  acc[MH*4+3][3] = mfma16x16x32(a3, b3, acc[MH*4+3][3]);
  __builtin_amdgcn_s_setprio(0);
  if constexpr (VMN == 6) asm volatile("s_waitcnt vmcnt(6)" ::: "memory");
  if constexpr (VMN == 0) asm volatile("s_waitcnt vmcnt(0)" ::: "memory");
  __builtin_amdgcn_s_barrier();
}

// 256x256, BK=64, 8 waves, 8-phase interleave (r16-proven schedule).
// EPI 0: qkv -> q/k/v [head][MPAD][64]; EPI 2: gelu -> bf16 [M][3072];
// EPI 3: f32 residual. KT compile-time (768 / 3072).
template<int EPI, int KT>
__global__ __launch_bounds__(512)
void gemm256(const bf16* __restrict__ A, const bf16* __restrict__ Bt,
             const float* __restrict__ bias, int Mreal,
             const float* __restrict__ fin, float* __restrict__ fout,
             bf16* __restrict__ ob0, bf16* __restrict__ ob1, bf16* __restrict__ ob2) {
  __shared__ __align__(16) char SMEM[131072];
  char* const A0k0 = SMEM;
  char* const A0k1 = SMEM + 16384;
  char* const B0k0 = SMEM + 32768;
  char* const B0k1 = SMEM + 49152;
  char* const A1k0 = SMEM + 65536;
  char* const A1k1 = SMEM + 81920;
  char* const B1k0 = SMEM + 98304;
  char* const B1k1 = SMEM + 114688;
  const int tid = threadIdx.x;
  const int lane = tid & 63, wv = tid >> 6;     // wv 0..7
  const int lr = lane & 15, hi = lane >> 4;
  const int wm = wv >> 2, wn = wv & 3;          // 2 x 4 wave grid

  const int gx = gridDim.x;
  const int nwg = gx * gridDim.y;
  int lin = blockIdx.y * gx + blockIdx.x;
  {
    const int q8 = nwg >> 3, r8 = nwg & 7;
    const int xcd = lin & 7, pos = lin >> 3;
    lin = (xcd < r8 ? xcd * (q8 + 1) : r8 * (q8 + 1) + (xcd - r8) * q8) + pos;
  }
  const size_t arow0 = (size_t)(lin / gx) * 256;
  const size_t brow0 = (size_t)(lin % gx) * 256;

  f32x4 acc[8][4] = {};
  short8 b0{}, b1{}, b2{}, b3{};
  constexpr int nt = KT >> 6;          // 12 (K=768) / 48 (K=3072) -- even

  // per-thread hoisted bases
  const int r0 = tid >> 2;
  const int c0 = (tid & 3) ^ ((r0 >> 1) & 3);
  const bf16* const gA0 = A  + (arow0 + r0) * (size_t)KT + c0 * 8;
  const bf16* const gA1 = gA0 + (size_t)128 * KT;
  const bf16* const gB0 = Bt + (brow0 + r0) * (size_t)KT + c0 * 8;
  const bf16* const gB1 = gB0 + (size_t)128 * KT;
  const int sdoff = tid << 4;
  const int cpos  = hi ^ ((lr >> 1) & 3);
  const int aoffB = (wm * 128 + lr) * 64 + (cpos << 4);
  const int boffB = (wn * 64 + lr) * 64 + (cpos << 4);

  auto stageU = [&](bool isB, int kt, int kh, char* dst) {
    if (kt >= nt) return;
    const int koff = (kt << 6) + (kh << 5);
    gload_lds16((isB ? gB0 : gA0) + koff, dst + sdoff);
    gload_lds16((isB ? gB1 : gA1) + koff, dst + sdoff + 8192);
  };

  // prologue (FIFO order = ledger order): tile0's 4 units, tile1's first 3
  stageU(true,  0, 0, B0k0);
  stageU(false, 0, 0, A0k0);
  stageU(true,  0, 1, B0k1);
  stageU(false, 0, 1, A0k1);
  stageU(true,  1, 0, B1k0);
  stageU(false, 1, 0, A1k0);
  stageU(true,  1, 1, B1k1);
  asm volatile("s_waitcnt vmcnt(6)" ::: "memory");   // tile0 fully landed
  __builtin_amdgcn_s_barrier();

  constexpr int niter = nt >> 1;
  for (int it = 0; it < niter - 1; ++it) {
    const int t = it * 2;
    const int kf1 = ((t+1) << 6) + 32, kf20 = (t+2) << 6, kf21 = kf20 + 32;
    const int kf30 = (t+3) << 6, kf31 = kf30 + 32;
    gphase<0,true ,-1>(A0k0, B0k0, aoffB, boffB, acc, b0,b1,b2,b3, gA0, gA1, A1k1, sdoff, kf1,  true);
    gphase<1,false,-1>(A0k0, B0k0, aoffB, boffB, acc, b0,b1,b2,b3, gB0, gB1, B0k0, sdoff, kf20, true);
    gphase<0,true ,-1>(A0k1, B0k1, aoffB, boffB, acc, b0,b1,b2,b3, gA0, gA1, A0k0, sdoff, kf20, true);
    gphase<1,false, 6>(A0k1, B0k1, aoffB, boffB, acc, b0,b1,b2,b3, gB0, gB1, B0k1, sdoff, kf21, true);
    gphase<0,true ,-1>(A1k0, B1k0, aoffB, boffB, acc, b0,b1,b2,b3, gA0, gA1, A0k1, sdoff, kf21, true);
    gphase<1,false,-1>(A1k0, B1k0, aoffB, boffB, acc, b0,b1,b2,b3, gB0, gB1, B1k0, sdoff, kf30, true);
    gphase<0,true ,-1>(A1k1, B1k1, aoffB, boffB, acc, b0,b1,b2,b3, gA0, gA1, A1k0, sdoff, kf30, true);
    gphase<1,false, 6>(A1k1, B1k1, aoffB, boffB, acc, b0,b1,b2,b3, gB0, gB1, B1k1, sdoff, kf31, true);
  }
  {  // final iteration: tiles nt-2, nt-1; out-of-range stages skipped; drain
    const int t = nt - 2;
    const int kf1 = ((t+1) << 6) + 32;
    gphase<0,true ,-1>(A0k0, B0k0, aoffB, boffB, acc, b0,b1,b2,b3, gA0, gA1, A1k1, sdoff, kf1, true);
    gphase<1,false,-1>(A0k0, B0k0, aoffB, boffB, acc, b0,b1,b2,b3, gB0, gB1, B0k0, sdoff, 0, false);
    gphase<0,true ,-1>(A0k1, B0k1, aoffB, boffB, acc, b0,b1,b2,b3, gA0, gA1, A0k0, sdoff, 0, false);
    gphase<1,false, 0>(A0k1, B0k1, aoffB, boffB, acc, b0,b1,b2,b3, gB0, gB1, B0k1, sdoff, 0, false);
    gphase<0,true ,-1>(A1k0, B1k0, aoffB, boffB, acc, b0,b1,b2,b3, gA0, gA1, A0k1, sdoff, 0, false);
    gphase<1,false,-1>(A1k0, B1k0, aoffB, boffB, acc, b0,b1,b2,b3, gB0, gB1, B1k0, sdoff, 0, false);
    gphase<0,true ,-1>(A1k1, B1k1, aoffB, boffB, acc, b0,b1,b2,b3, gA0, gA1, A1k0, sdoff, 0, false);
    gphase<1,false, 0>(A1k1, B1k1, aoffB, boffB, acc, b0,b1,b2,b3, gB0, gB1, B1k1, sdoff, 0, false);
  }

  if constexpr (EPI == 0) {
    // ---- qkv: wave-local LDS-staged bf16 drain to q/k/v [head][MPAD][64] ----
    __syncthreads();
    char* ep = SMEM + wv * 16384;              // [128 rows][64 cols bf16]
    #pragma unroll
    for (int m = 0; m < 8; ++m) {
      #pragma unroll
      for (int n = 0; n < 4; ++n) {
        const int col = n * 16 + lr;
        const float bv = bias[(int)brow0 + wn * 64 + col];
        #pragma unroll
        for (int e = 0; e < 4; ++e) {
          const int row_l = m * 16 + hi * 4 + e;
          const int byte = row_l * 128 + col * 2;
          *(bf16*)(ep + (byte ^ ((row_l & 7) << 4))) = __float2bfloat16(acc[m][n][e] + bv);
        }
      }
    }
    __syncthreads();
    // wave's 64-col span = one head-d chunk: which/head constant per wave
    const int hchunk = ((int)brow0 + wn * 64) >> 6;      // 0..35
    const int which = hchunk / 12, head = hchunk % 12;
    bf16* dstb = (which == 0) ? ob0 : ((which == 1) ? ob1 : ob2);
    #pragma unroll
    for (int u = 0; u < 16; ++u) {
      const int unit = u * 64 + lane;          // 1024 units of 16 B per wave
      const int row_l = unit >> 3, slot = unit & 7;
      const int byte = row_l * 128 + slot * 16;
      const short8 val = *(const short8*)(ep + (byte ^ ((row_l & 7) << 4)));
      const int grow = (int)arow0 + wm * 128 + row_l;
      if (grow < Mreal)
        *(short8*)&dstb[((size_t)head * MPAD + grow) * 64 + slot * 8] = val;
    }
  } else if constexpr (EPI == 2) {
    // ---- gelu + LDS-staged coalesced bf16 stores (wave-local 8 KB region) ----
    char* ep = SMEM + wv * 8192;               // [64 rows][64 cols bf16]
    #pragma unroll
    for (int h = 0; h < 2; ++h) {
      #pragma unroll
      for (int m2 = 0; m2 < 4; ++m2) {
        #pragma unroll
        for (int n = 0; n < 4; ++n) {
          const int col = n * 16 + lr;
          const float bv = bias[(int)brow0 + wn * 64 + col];
          #pragma unroll
          for (int e = 0; e < 4; ++e) {
            const int row_l = m2 * 16 + hi * 4 + e;
            const float v = gelu_f(acc[h * 4 + m2][n][e] + bv);
            *(bf16*)(ep + row_l * 128 + (((col >> 3) ^ (row_l & 7)) << 4) + ((col & 7) << 1))
                = __float2bfloat16(v);
          }
        }
      }
      #pragma unroll
      for (int p = 0; p < 8; ++p) {
        const int row_l = p * 8 + (lane >> 3);
        const int slot  = lane & 7;
        const short8 val = *(const short8*)(ep + row_l * 128 + ((slot ^ (row_l & 7)) << 4));
        const size_t grow = arow0 + wm * 128 + h * 64 + row_l;
        const int gcol = (int)brow0 + wn * 64 + slot * 8;
        *(short8*)&ob0[grow * 3072 + gcol] = val;
      }
    }
  } else {
    // ---- EPI 3: dense f32 residual ----
    #pragma unroll
    for (int n = 0; n < 4; ++n) {
      const int col = (int)brow0 + wn * 64 + n * 16 + lr;
      const float bv = bias[col];
      #pragma unroll
      for (int m = 0; m < 8; ++m) {
        #pragma unroll
        for (int e = 0; e < 4; ++e) {
          const size_t row = arow0 + wm * 128 + m * 16 + hi * 4 + e;
          const size_t idx = row * 768 + col;
          fout[idx] = fin[idx] + acc[m][n][e] + bv;
        }
      }
    }
  }
}

// ---------------- fused window attention (r12-proven, untouched) -------------
__global__ __launch_bounds__(512, 2)
void attn_kernel(const bf16* __restrict__ qb, const bf16* __restrict__ kb,
                 const bf16* __restrict__ vb, const float* __restrict__ rph,
                 const float* __restrict__ rpw, bf16* __restrict__ aout) {
  __shared__ __align__(16) char SM[65248];
  bf16* pbh    = (bf16*)SM;
  bf16* pbw    = (bf16*)(SM + 4096);
  bf16* Gh     = (bf16*)(SM + 8192);
  bf16* Gw     = (bf16*)(SM + 23168);
  char* klds   = SM;                    // [200 rows][128 B], XOR-swizzled
  char* vtb    = SM + 25600;            // [64 d][448 B], XOR-swizzled
  bf16* relh_s = (bf16*)(SM + 54272);   // [196][14]
  bf16* relw_s = (bf16*)(SM + 59760);   // [196][14]

  const int bh = blockIdx.x;             // 0..2399
  const int win = bh / 12, head = bh % 12;
  const size_t base = ((size_t)head * MPAD + win * 196) * 64;
  const bf16* Q  = qb + base;
  const bf16* Kp = kb + base;
  const bf16* Vp = vb + base;
  const int tid = threadIdx.x, lane = tid & 63, wv = tid >> 6;   // wv 0..7
  const int lr = lane & 15, hi = lane >> 4;

  for (int i = tid; i < 32 * 64; i += 512) {
    const int r = i >> 6, c = i & 63;
    const bool ok = r < 27;
    pbh[i] = __float2bfloat16(ok ? rph[r * 64 + c] : 0.f);
    pbw[i] = __float2bfloat16(ok ? rpw[r * 64 + c] : 0.f);
  }
  __syncthreads();
  {
    short8 bh00 = *(const short8*)&pbh[(lr) * 64 + hi * 8];
    short8 bh01 = *(const short8*)&pbh[(lr) * 64 + 32 + hi * 8];
    short8 bh10 = *(const short8*)&pbh[(16 + lr) * 64 + hi * 8];
    short8 bh11 = *(const short8*)&pbh[(16 + lr) * 64 + 32 + hi * 8];
    short8 bw00 = *(const short8*)&pbw[(lr) * 64 + hi * 8];
    short8 bw01 = *(const short8*)&pbw[(lr) * 64 + 32 + hi * 8];
    short8 bw10 = *(const short8*)&pbw[(16 + lr) * 64 + hi * 8];
    short8 bw11 = *(const short8*)&pbw[(16 + lr) * 64 + 32 + hi * 8];
    for (int mt = wv; mt < 13; mt += 8) {
      const short8 a0 = *(const short8*)&Q[(mt * 16 + lr) * 64 + hi * 8];
      const short8 a1 = *(const short8*)&Q[(mt * 16 + lr) * 64 + 32 + hi * 8];
      f32x4 g0 = {}, g1 = {}, g2 = {}, g3 = {};
      g0 = mfma16x16x32(a0, bh00, g0); g0 = mfma16x16x32(a1, bh01, g0);
      g1 = mfma16x16x32(a0, bh10, g1); g1 = mfma16x16x32(a1, bh11, g1);
      g2 = mfma16x16x32(a0, bw00, g2); g2 = mfma16x16x32(a1, bw01, g2);
      g3 = mfma16x16x32(a0, bw10, g3); g3 = mfma16x16x32(a1, bw11, g3);
      #pragma unroll
      for (int e = 0; e < 4; ++e) {
        const int row = mt * 16 + hi * 4 + e;
        Gh[row * 36 + lr]      = __float2bfloat16(g0[e]);
        Gh[row * 36 + 16 + lr] = __float2bfloat16(g1[e]);
        Gw[row * 36 + lr]      = __float2bfloat16(g2[e]);
        Gw[row * 36 + 16 + lr] = __float2bfloat16(g3[e]);
      }
    }
  }
  __syncthreads();
  bf16 ghr[6], gwr[6];
  #pragma unroll
  for (int t = 0; t < 6; ++t) {
    const int i = tid + t * 512;
    if (i < 196 * 14) {
      const int q = i / 14, kk = i - (i / 14) * 14;
      const int rh = q / 14 - kk + 13;
      const int rw2 = q - (q / 14) * 14 - kk + 13;
      ghr[t] = Gh[q * 36 + rh];
      gwr[t] = Gw[q * 36 + rw2];
    }
  }
  __syncthreads();
  #pragma unroll
  for (int t = 0; t < 6; ++t) {
    const int i = tid + t * 512;
    if (i < 196 * 14) { relh_s[i] = ghr[t]; relw_s[i] = gwr[t]; }
  }
  for (int c = wv; c < 25; c += 8) {
    const int row = c * 8 + (lane >> 3);
    const int ch  = (lane & 7) ^ (row & 7);
    gload_lds16(Kp + row * 64 + ch * 8, klds + c * 1024);
  }
  for (int i = tid; i < 196 * 8; i += 512) {
    const int key = i >> 3, dg = (i & 7) * 8;
    const short8 v = *(const short8*)&Vp[key * 64 + dg];
    #pragma unroll
    for (int j = 0; j < 8; ++j) {
      const int idx = (dg + j) * 448 + key * 2;
      *(bf16*)(vtb + (idx ^ (j << 4))) = ((const bf16*)&v)[j];
    }
  }
  for (int i = tid; i < 64 * 28; i += 512) {
    const int d = i / 28, key = 196 + i - (i / 28) * 28;
    const int idx = d * 448 + key * 2;
    *(bf16*)(vtb + (idx ^ ((d & 7) << 4))) = __float2bfloat16(0.f);
  }
  __syncthreads();

  for (int qt = wv; qt < 13; qt += 8) {
    const int q = qt * 16 + lr;
    const int qc = q < 196 ? q : 195;
    const short8 bq0 = *(const short8*)&Q[(qt * 16 + lr) * 64 + hi * 8];
    const short8 bq1 = *(const short8*)&Q[(qt * 16 + lr) * 64 + 32 + hi * 8];
    f32x4 s[13];
    __builtin_amdgcn_s_setprio(1);
    #pragma unroll
    for (int nt = 0; nt < 13; ++nt) {
      const int key = nt * 16 + lr;
      const char* kr = klds + key * 128;
      const short8 ka0 = *(const short8*)(kr + (((hi) ^ (key & 7)) << 4));
      const short8 ka1 = *(const short8*)(kr + (((hi + 4) ^ (key & 7)) << 4));
      f32x4 z = {};
      z = mfma16x16x32(ka0, bq0, z);
      z = mfma16x16x32(ka1, bq1, z);
      s[nt] = z;
    }
    __builtin_amdgcn_s_setprio(0);
    float mx = -3.0e38f;
    #pragma unroll
    for (int nt = 0; nt < 13; ++nt) {
      #pragma unroll
      for (int e = 0; e < 4; ++e) {
        const int key = nt * 16 + hi * 4 + e;
        const int kh = key / 14, kw = key - kh * 14;
        float v = s[nt][e] * 0.125f + __bfloat162float(relh_s[qc * 14 + kh])
                                    + __bfloat162float(relw_s[qc * 14 + kw]);
        v = (key < 196) ? v : -3.0e38f;
        s[nt][e] = v;
        mx = fmaxf(mx, v);
      }
    }
    mx = fmaxf(mx, __shfl_xor(mx, 16));
    mx = fmaxf(mx, __shfl_xor(mx, 32));
    float sm = 0.f;
    uint32_t pk0[14], pk1[14];
    #pragma unroll
    for (int nt = 0; nt < 13; ++nt) {
      const float p0 = __expf(s[nt][0] - mx);
      const float p1 = __expf(s[nt][1] - mx);
      const float p2 = __expf(s[nt][2] - mx);
      const float p3 = __expf(s[nt][3] - mx);
      sm += (p0 + p1) + (p2 + p3);
      pk0[nt] = cvtpk(p0, p1);
      pk1[nt] = cvtpk(p2, p3);
    }
    pk0[13] = 0u; pk1[13] = 0u;
    sm += __shfl_xor(sm, 16);
    sm += __shfl_xor(sm, 32);
    const float rinv = 1.f / sm;
    f32x4 o[4] = {};
    #pragma unroll
    for (int kk = 0; kk < 7; ++kk) {
      const uint32_t x0 = pk0[2 * kk],     x1 = pk1[2 * kk];
      const uint32_t y0 = pk0[2 * kk + 1], y1 = pk1[2 * kk + 1];
      const uint32_t s0 = (hi < 2) ? y0 : x0, s1 = (hi < 2) ? y1 : x1;
      const uint32_t t0 = __shfl_xor(s0, 32), t1 = __shfl_xor(s1, 32);
      const uint32_t o0 = (hi < 2) ? x0 : y0, o1 = (hi < 2) ? x1 : y1;
      const bool sendOwn = (hi == 1) || (hi == 2);
      const uint32_t u0 = sendOwn ? o0 : t0, u1 = sendOwn ? o1 : t1;
      const uint32_t r0 = __shfl_xor(u0, 16), r1 = __shfl_xor(u1, 16);
      union { uint32_t u[4]; short8 v; } pf;
      pf.u[0] = (hi == 0) ? x0 : ((hi == 2) ? t0 : r0);
      pf.u[1] = (hi == 0) ? x1 : ((hi == 2) ? t1 : r1);
      pf.u[2] = (hi == 3) ? y0 : ((hi == 1) ? t0 : r0);
      pf.u[3] = (hi == 3) ? y1 : ((hi == 1) ? t1 : r1);
      __builtin_amdgcn_s_setprio(1);
      #pragma unroll
      for (int n2 = 0; n2 < 4; ++n2) {
        const int d = n2 * 16 + lr;
        const int idx = d * 448 + (kk * 32 + hi * 8) * 2;
        const short8 va = *(const short8*)(vtb + (idx ^ ((lr & 7) << 4)));
        o[n2] = mfma16x16x32(va, pf.v, o[n2]);
      }
      __builtin_amdgcn_s_setprio(0);
    }
    if (q < 196) {
      bf16* orow = aout + ((size_t)head * MPAD + win * 196 + q) * 64;
      #pragma unroll
      for (int n2 = 0; n2 < 4; ++n2) {
        uint32_t d0 = cvtpk(o[n2][0] * rinv, o[n2][1] * rinv);
        uint32_t d1 = cvtpk(o[n2][2] * rinv, o[n2][3] * rinv);
        uint32_t* dst = (uint32_t*)&orow[n2 * 16 + hi * 4];
        dst[0] = d0; dst[1] = d1;
      }
    }
  }
}

// ---------------- host ----------------
extern "C" void kernel_launch(void* const* d_in, const int* in_sizes, int n_in,
                              void* d_out, int out_size, void* d_ws, size_t ws_size,
                              hipStream_t stream) {
  (void)in_sizes; (void)n_in; (void)out_size; (void)ws_size;
  const float* x      = (const float*)d_in[0];
  const float* ln1_g  = (const float*)d_in[1];
  const float* ln1_b  = (const float*)d_in[2];
  const float* qkv_w  = (const float*)d_in[3];
  const float* qkv_b  = (const float*)d_in[4];
  const float* proj_w = (const float*)d_in[5];
  const float* proj_b = (const float*)d_in[6];
  const float* rph    = (const float*)d_in[7];
  const float* rpw    = (const float*)d_in[8];
  const float* ln2_g  = (const float*)d_in[9];
  const float* ln2_b  = (const float*)d_in[10];
  const float* w1     = (const float*)d_in[11];
  const float* b1v    = (const float*)d_in[12];
  const float* w2     = (const float*)d_in[13];
  const float* b2v    = (const float*)d_in[14];
  float* outp = (float*)d_out;   // also serves as x1 (written by proj epilogue)

  char* ws = (char*)d_ws;
  size_t off = 0;
  auto alloc = [&](size_t bytes) { char* p = ws + off; off += (bytes + 255) & ~(size_t)255; return p; };
  bf16* qkv_wt  = (bf16*)alloc((size_t)2304 * 768 * 2);
  bf16* proj_wt = (bf16*)alloc((size_t)768 * 768 * 2);
  bf16* w1t     = (bf16*)alloc((size_t)3072 * 768 * 2);
  bf16* w2t     = (bf16*)alloc((size_t)768 * 3072 * 2);
  const size_t szB1 = (size_t)MPAD * 768 * 2;
  const size_t szB2 = (size_t)TOK2 * 768 * 2;
  char* regB = alloc(szB1 > szB2 ? szB1 : szB2);
  const size_t szQKV = (size_t)3 * 12 * MPAD * 64 * 2;
  const size_t szH   = (size_t)TOK2 * 3072 * 2;
  char* regC = alloc(szQKV > szH ? szQKV : szH);

  bf16* xnwin   = (bf16*)regB;
  bf16* attnout = (bf16*)regB;
  bf16* xn2     = (bf16*)regB;
  bf16* qbuf    = (bf16*)regC;                       // [12][MPAD][64]
  bf16* kbuf    = qbuf + (size_t)12 * MPAD * 64;
  bf16* vbuf    = kbuf + (size_t)12 * MPAD * 64;
  bf16* hbuf    = (bf16*)regC;

  transpose_cast<<<dim3(2304 / 32, 768 / 32), 256, 0, stream>>>(qkv_w, qkv_wt, 768, 2304);
  transpose_cast<<<dim3(768 / 32, 768 / 32), 256, 0, stream>>>(proj_w, proj_wt, 768, 768);
  transpose_cast<<<dim3(3072 / 32, 768 / 32), 256, 0, stream>>>(w1, w1t, 768, 3072);
  transpose_cast<<<dim3(768 / 32, 3072 / 32), 256, 0, stream>>>(w2, w2t, 3072, 768);

  ln1_partition<<<dim3(MROWS / 4), 256, 0, stream>>>(x, ln1_g, ln1_b, xnwin);

  // qkv on the 8-phase 256^2 kernel (M padded to 39424)
  gemm256<0, 768><<<dim3(2304 / 256, MPAD / 256), 512, 0, stream>>>(
      xnwin, qkv_wt, qkv_b, MROWS, nullptr, nullptr, qbuf, kbuf, vbuf);

  attn_kernel<<<dim3(2400), 512, 0, stream>>>(qbuf, kbuf, vbuf, rph, rpw, attnout);

  gemm_bf16<1><<<dim3(768 / 128, MPAD / 128), 256, 0, stream>>>(
      attnout, proj_wt, proj_b, 768, MROWS, x, outp, nullptr, nullptr, nullptr);

  ln2_kernel<<<dim3(TOK2 / 4), 256, 0, stream>>>(outp, ln2_g, ln2_b, xn2);

  // MLP on the 8-phase 256^2 kernel
  gemm256<2, 768><<<dim3(3072 / 256, TOK2 / 256), 512, 0, stream>>>(
      xn2, w1t, b1v, TOK2, nullptr, nullptr, hbuf, nullptr, nullptr);
  gemm256<3, 3072><<<dim3(768 / 256, TOK2 / 256), 512, 0, stream>>>(
      hbuf, w2t, b2v, TOK2, outp, outp, nullptr, nullptr, nullptr);
}

// Round 23
// 953.081 us; speedup vs baseline: 1.1112x; 1.0933x over previous
//
#include <hip/hip_runtime.h>
#include <hip/hip_bf16.h>
#include <cstdint>
#include <cstddef>

using bf16 = __hip_bfloat16;
typedef __attribute__((ext_vector_type(8))) short short8;
typedef __attribute__((ext_vector_type(4))) float f32x4;

typedef __attribute__((address_space(1))) const void as1_void;
typedef __attribute__((address_space(3))) void as3_void;

__device__ __forceinline__ f32x4 mfma16x16x32(short8 a, short8 b, f32x4 c) {
  return __builtin_amdgcn_mfma_f32_16x16x32_bf16(a, b, c, 0, 0, 0);
}

__device__ __forceinline__ void gload_lds16(const void* g, void* l) {
  __builtin_amdgcn_global_load_lds((as1_void*)g, (as3_void*)l, 16, 0, 0);
}

__device__ __forceinline__ uint32_t cvtpk(float a, float b) {
  uint32_t r;
  asm("v_cvt_pk_bf16_f32 %0, %1, %2" : "=v"(r) : "v"(a), "v"(b));
  return r;
}

__device__ __forceinline__ float gelu_f(float v) {
  const float u = 0.7978845608f * v * (1.f + 0.044715f * v * v);
  const float e = __expf(-2.f * fabsf(u));
  const float t = (1.f - e) / (1.f + e);
  return 0.5f * v * (1.f + (u < 0.f ? -t : t));
}

// ---------------- problem constants ----------------
static constexpr int MROWS = 39200;
static constexpr int MPAD  = 39424;   // 154 x 256 (256-tile friendly)
static constexpr int TOK2  = 32768;

// ---------------- weight transpose+cast:  in f32 [K][N] -> out bf16 [N][K] ----
__global__ __launch_bounds__(256)
void transpose_cast(const float* __restrict__ in, bf16* __restrict__ out, int K, int N) {
  __shared__ float t[32][33];
  const int tx = threadIdx.x & 31, ty = threadIdx.x >> 5;
  const int bx = blockIdx.x, by = blockIdx.y;
  const int x = bx * 32 + tx;
  for (int r = ty; r < 32; r += 8)
    t[r][tx] = in[(size_t)(by * 32 + r) * N + x];
  __syncthreads();
  const int xo = by * 32 + tx;
  for (int r = ty; r < 32; r += 8)
    out[(size_t)(bx * 32 + r) * K + xo] = __float2bfloat16(t[tx][r]);
}

// ---------------- LN1 + window partition -> bf16 [MPAD][768] ----------------
__global__ __launch_bounds__(256)
void ln1_partition(const float* __restrict__ x, const float* __restrict__ g,
                   const float* __restrict__ bb, bf16* __restrict__ out) {
  const int token = blockIdx.x * 4 + (threadIdx.x >> 6);
  const int lane = threadIdx.x & 63;
  const int win = token / 196, tok = token % 196;
  const int b_ = win / 25, wh = (win / 5) % 5, ww = win % 5;
  const int i = tok / 14, j = tok % 14;
  const int h = wh * 14 + i, w = ww * 14 + j;
  bf16* o = out + (size_t)token * 768;
  if (h >= 64 || w >= 64) {
    for (int t = 0; t < 12; ++t) o[lane + 64 * t] = __float2bfloat16(0.f);
    return;
  }
  const float* src = x + ((size_t)((b_ * 64 + h) * 64 + w)) * 768;
  float vals[12], s = 0.f, ss = 0.f;
  #pragma unroll
  for (int t = 0; t < 12; ++t) {
    float v = src[lane + 64 * t];
    vals[t] = v; s += v; ss += v * v;
  }
  #pragma unroll
  for (int d = 32; d > 0; d >>= 1) { s += __shfl_xor(s, d); ss += __shfl_xor(ss, d); }
  const float mu = s * (1.f / 768.f);
  const float var = ss * (1.f / 768.f) - mu * mu;
  const float inv = rsqrtf(var + 1e-6f);
  #pragma unroll
  for (int t = 0; t < 12; ++t) {
    const int c = lane + 64 * t;
    o[c] = __float2bfloat16((vals[t] - mu) * inv * g[c] + bb[c]);
  }
}

// ---------------- LN2 on x1 (f32, dense [32768][768]) -> bf16 ----------------
__global__ __launch_bounds__(256)
void ln2_kernel(const float* __restrict__ x1, const float* __restrict__ g,
                const float* __restrict__ bb, bf16* __restrict__ out) {
  const int token = blockIdx.x * 4 + (threadIdx.x >> 6);
  const int lane = threadIdx.x & 63;
  const float* src = x1 + (size_t)token * 768;
  bf16* o = out + (size_t)token * 768;
  float vals[12], s = 0.f, ss = 0.f;
  #pragma unroll
  for (int t = 0; t < 12; ++t) {
    float v = src[lane + 64 * t];
    vals[t] = v; s += v; ss += v * v;
  }
  #pragma unroll
  for (int d = 32; d > 0; d >>= 1) { s += __shfl_xor(s, d); ss += __shfl_xor(ss, d); }
  const float mu = s * (1.f / 768.f);
  const float var = ss * (1.f / 768.f) - mu * mu;
  const float inv = rsqrtf(var + 1e-6f);
  #pragma unroll
  for (int t = 0; t < 12; ++t) {
    const int c = lane + 64 * t;
    o[c] = __float2bfloat16((vals[t] - mu) * inv * g[c] + bb[c]);
  }
}

// ---------------- 128x128 GEMM (proj only; r5/r6-proven loop) ------------
// EPI 1 epilogue: LDS-staged f32 drain (256-B contiguous row segments) to
// kill the 64-B-segment read/write amplification of the direct scatter.
template<int EPI>
__global__ __launch_bounds__(256)
void gemm_bf16(const bf16* __restrict__ A, const bf16* __restrict__ Bt,
               const float* __restrict__ bias, int K, int Mreal,
               const float* __restrict__ fin, float* __restrict__ fout,
               bf16* __restrict__ ob0, bf16* __restrict__ ob1, bf16* __restrict__ ob2) {
  __shared__ __align__(16) bf16 SMEM[16384];                 // 32 KB
  bf16* const lA0 = SMEM;
  bf16* const lA1 = SMEM + 4096;
  bf16* const lB0 = SMEM + 8192;
  bf16* const lB1 = SMEM + 12288;
  const int tid = threadIdx.x;
  const int lane = tid & 63, wv = tid >> 6;
  const int lr = lane & 15, hi = lane >> 4;
  const int wm = wv >> 1, wn = wv & 1;

  const int gx = gridDim.x;
  const int nwg = gx * gridDim.y;
  int lin = blockIdx.y * gx + blockIdx.x;
  {
    const int q8 = nwg >> 3, r8 = nwg & 7;
    const int xcd = lin & 7, pos = lin >> 3;
    lin = (xcd < r8 ? xcd * (q8 + 1) : r8 * (q8 + 1) + (xcd - r8) * q8) + pos;
  }
  const size_t arow0 = (size_t)(lin / gx) * 128;
  const size_t brow0 = (size_t)(lin % gx) * 128;
  f32x4 acc[4][4] = {};

  auto stage = [&](bf16* bufA, bf16* bufB, int kt) {
    const int k0 = kt * 32;
    #pragma unroll
    for (int it = 0; it < 2; ++it) {
      const int seg = it * 256 + tid;
      const int row = seg >> 2, kq = seg & 3;
      const size_t dst = (size_t)(it * 256 + wv * 64) * 8;
      if constexpr (EPI == 1) {
        const int k = k0 + kq * 8;   // A layout: [head][MPAD][64]
        gload_lds16(A + ((size_t)(k >> 6) * MPAD + arow0 + row) * 64 + (k & 63), bufA + dst);
      } else {
        gload_lds16(A + (arow0 + row) * K + k0 + kq * 8, bufA + dst);
      }
      gload_lds16(Bt + (brow0 + row) * K + k0 + kq * 8, bufB + dst);
    }
  };
  auto compute = [&](const bf16* bufA, const bf16* bufB) {
    short8 af[4], bfr[4];
    #pragma unroll
    for (int m = 0; m < 4; ++m) af[m] = *(const short8*)&bufA[(wm * 64 + m * 16 + lr) * 32 + hi * 8];
    #pragma unroll
    for (int n = 0; n < 4; ++n) bfr[n] = *(const short8*)&bufB[(wn * 64 + n * 16 + lr) * 32 + hi * 8];
    #pragma unroll
    for (int m = 0; m < 4; ++m)
      #pragma unroll
      for (int n = 0; n < 4; ++n)
        acc[m][n] = mfma16x16x32(af[m], bfr[n], acc[m][n]);
  };

  const int nt = K >> 5;               // even
  stage(lA0, lB0, 0);
  __syncthreads();
  for (int t = 0; t < nt; t += 2) {
    if (t + 1 < nt) stage(lA1, lB1, t + 1);
    compute(lA0, lB0);
    __syncthreads();
    if (t + 2 < nt) stage(lA0, lB0, t + 2);
    compute(lA1, lB1);
    __syncthreads();
  }

  // ---- EPI 1: proj residual via wave-local LDS staging (two 32-row passes)
  {
    char* ep = (char*)SMEM + wv * 8192;        // [32 rows][64 cols f32]
    #pragma unroll
    for (int p = 0; p < 2; ++p) {
      #pragma unroll
      for (int m2 = 0; m2 < 2; ++m2) {
        const int m = p * 2 + m2;
        #pragma unroll
        for (int n = 0; n < 4; ++n) {
          const int col = n * 16 + lr;
          const float bv = bias[(int)brow0 + wn * 64 + col];
          #pragma unroll
          for (int e = 0; e < 4; ++e) {
            const int row_l = m2 * 16 + hi * 4 + e;
            *(float*)(ep + row_l * 256 + col * 4) = acc[m][n][e] + bv;
          }
        }
      }
      #pragma unroll
      for (int u = 0; u < 8; ++u) {
        const int unit = u * 64 + lane;        // 512 16-B units per pass
        const int row_l = unit >> 4, ucol = unit & 15;
        const int row = (int)arow0 + wm * 64 + p * 32 + row_l;
        if (row < Mreal) {
          const int win = row / 196, tok = row % 196;
          const int b_ = win / 25, wh = (win / 5) % 5, ww = win % 5;
          const int i2 = tok / 14, j2 = tok % 14;
          const int h2 = wh * 14 + i2, w2 = ww * 14 + j2;
          if (h2 < 64 && w2 < 64) {
            const size_t idx = ((size_t)((b_ * 64 + h2) * 64 + w2)) * 768
                             + (int)brow0 + wn * 64 + ucol * 4;
            const f32x4 sv = *(const f32x4*)(ep + row_l * 256 + ucol * 16);
            const f32x4 fv = *(const f32x4*)&fin[idx];
            f32x4 ov = {sv[0] + fv[0], sv[1] + fv[1], sv[2] + fv[2], sv[3] + fv[3]};
            *(f32x4*)&fout[idx] = ov;
          }
        }
      }
    }
  }
}

// ---------------- m201-style 8-phase 256x256 GEMM (addr-hoisted, K templated)
template<int MH, bool READB, int VMN>
__device__ __forceinline__ void gphase(
    const char* aR, const char* bR, int aoffB, int boffB,
    f32x4 (&acc)[8][4], short8& b0, short8& b1, short8& b2, short8& b3,
    const bf16* g0, const bf16* g1, char* sdst, int sdoff, int koff, bool doStage) {
  short8 a0 = *(const short8*)(aR + aoffB + (MH * 64 +  0) * 64);
  short8 a1 = *(const short8*)(aR + aoffB + (MH * 64 + 16) * 64);
  short8 a2 = *(const short8*)(aR + aoffB + (MH * 64 + 32) * 64);
  short8 a3 = *(const short8*)(aR + aoffB + (MH * 64 + 48) * 64);
  if constexpr (READB) {
    b0 = *(const short8*)(bR + boffB +  0 * 64);
    b1 = *(const short8*)(bR + boffB + 16 * 64);
    b2 = *(const short8*)(bR + boffB + 32 * 64);
    b3 = *(const short8*)(bR + boffB + 48 * 64);
  }
  if (doStage) {
    gload_lds16(g0 + koff, sdst + sdoff);
    gload_lds16(g1 + koff, sdst + sdoff + 8192);
  }
  __builtin_amdgcn_s_barrier();
  asm volatile("s_waitcnt lgkmcnt(0)" ::: "memory");
  __builtin_amdgcn_sched_barrier(0);
  __builtin_amdgcn_s_setprio(1);
  acc[MH*4+0][0] = mfma16x16x32(a0, b0, acc[MH*4+0][0]);
  acc[MH*4+0][1] = mfma16x16x32(a0, b1, acc[MH*4+0][1]);
  acc[MH*4+0][2] = mfma16x16x32(a0, b2, acc[MH*4+0][2]);
  acc[MH*4+0][3] = mfma16x16x32(a0, b3, acc[MH*4+0][3]);
  acc[MH*4+1][0] = mfma16x16x32(a1, b0, acc[MH*4+1][0]);
  acc[MH*4+1][1] = mfma16x16x32(a1, b1, acc[MH*4+1][1]);
  acc[MH*4+1][2] = mfma16x16x32(a1, b2, acc[MH*4+1][2]);
  acc[MH*4+1][3] = mfma16x16x32(a1, b3, acc[MH*4+1][3]);
  acc[MH*4+2][0] = mfma16x16x32(a2, b0, acc[MH*4+2][0]);
  acc[MH*4+2][1] = mfma16x16x32(a2, b1, acc[MH*4+2][1]);
  acc[MH*4+2][2] = mfma16x16x32(a2, b2, acc[MH*4+2][2]);
  acc[MH*4+2][3] = mfma16x16x32(a2, b3, acc[MH*4+2][3]);
  acc[MH*4+3][0] = mfma16x16x32(a3, b0, acc[MH*4+3][0]);
  acc[MH*4+3][1] = mfma16x16x32(a3, b1, acc[MH*4+3][1]);
  acc[MH*4+3][2] = mfma16x16x32(a3, b2, acc[MH*4+3][2]);
  acc[MH*4+3][3] = mfma16x16x32(a3, b3, acc[MH*4+3][3]);
  __builtin_amdgcn_s_setprio(0);
  if constexpr (VMN == 6) asm volatile("s_waitcnt vmcnt(6)" ::: "memory");
  if constexpr (VMN == 0) asm volatile("s_waitcnt vmcnt(0)" ::: "memory");
  __builtin_amdgcn_s_barrier();
}

// 256x256, BK=64, 8 waves, 8-phase interleave (r16/r20-proven schedule).
// EPI 0: qkv -> q/k/v [head][MPAD][64]; EPI 2: gelu -> bf16 [M][3072];
// EPI 3: f32 residual via LDS-staged coalesced drain. KT compile-time.
template<int EPI, int KT>
__global__ __launch_bounds__(512)
void gemm256(const bf16* __restrict__ A, const bf16* __restrict__ Bt,
             const float* __restrict__ bias, int Mreal,
             const float* __restrict__ fin, float* __restrict__ fout,
             bf16* __restrict__ ob0, bf16* __restrict__ ob1, bf16* __restrict__ ob2) {
  __shared__ __align__(16) char SMEM[131072];
  char* const A0k0 = SMEM;
  char* const A0k1 = SMEM + 16384;
  char* const B0k0 = SMEM + 32768;
  char* const B0k1 = SMEM + 49152;
  char* const A1k0 = SMEM + 65536;
  char* const A1k1 = SMEM + 81920;
  char* const B1k0 = SMEM + 98304;
  char* const B1k1 = SMEM + 114688;
  const int tid = threadIdx.x;
  const int lane = tid & 63, wv = tid >> 6;     // wv 0..7
  const int lr = lane & 15, hi = lane >> 4;
  const int wm = wv >> 2, wn = wv & 3;          // 2 x 4 wave grid

  const int gx = gridDim.x;
  const int nwg = gx * gridDim.y;
  int lin = blockIdx.y * gx + blockIdx.x;
  {
    const int q8 = nwg >> 3, r8 = nwg & 7;
    const int xcd = lin & 7, pos = lin >> 3;
    lin = (xcd < r8 ? xcd * (q8 + 1) : r8 * (q8 + 1) + (xcd - r8) * q8) + pos;
  }
  const size_t arow0 = (size_t)(lin / gx) * 256;
  const size_t brow0 = (size_t)(lin % gx) * 256;

  f32x4 acc[8][4] = {};
  short8 b0{}, b1{}, b2{}, b3{};
  constexpr int nt = KT >> 6;          // 12 (K=768) / 48 (K=3072) -- even

  // per-thread hoisted bases
  const int r0 = tid >> 2;
  const int c0 = (tid & 3) ^ ((r0 >> 1) & 3);
  const bf16* const gA0 = A  + (arow0 + r0) * (size_t)KT + c0 * 8;
  const bf16* const gA1 = gA0 + (size_t)128 * KT;
  const bf16* const gB0 = Bt + (brow0 + r0) * (size_t)KT + c0 * 8;
  const bf16* const gB1 = gB0 + (size_t)128 * KT;
  const int sdoff = tid << 4;
  const int cpos  = hi ^ ((lr >> 1) & 3);
  const int aoffB = (wm * 128 + lr) * 64 + (cpos << 4);
  const int boffB = (wn * 64 + lr) * 64 + (cpos << 4);

  auto stageU = [&](bool isB, int kt, int kh, char* dst) {
    if (kt >= nt) return;
    const int koff = (kt << 6) + (kh << 5);
    gload_lds16((isB ? gB0 : gA0) + koff, dst + sdoff);
    gload_lds16((isB ? gB1 : gA1) + koff, dst + sdoff + 8192);
  };

  // prologue (FIFO order = ledger order): tile0's 4 units, tile1's first 3
  stageU(true,  0, 0, B0k0);
  stageU(false, 0, 0, A0k0);
  stageU(true,  0, 1, B0k1);
  stageU(false, 0, 1, A0k1);
  stageU(true,  1, 0, B1k0);
  stageU(false, 1, 0, A1k0);
  stageU(true,  1, 1, B1k1);
  asm volatile("s_waitcnt vmcnt(6)" ::: "memory");   // tile0 fully landed
  __builtin_amdgcn_s_barrier();

  constexpr int niter = nt >> 1;
  for (int it = 0; it < niter - 1; ++it) {
    const int t = it * 2;
    const int kf1 = ((t+1) << 6) + 32, kf20 = (t+2) << 6, kf21 = kf20 + 32;
    const int kf30 = (t+3) << 6, kf31 = kf30 + 32;
    gphase<0,true ,-1>(A0k0, B0k0, aoffB, boffB, acc, b0,b1,b2,b3, gA0, gA1, A1k1, sdoff, kf1,  true);
    gphase<1,false,-1>(A0k0, B0k0, aoffB, boffB, acc, b0,b1,b2,b3, gB0, gB1, B0k0, sdoff, kf20, true);
    gphase<0,true ,-1>(A0k1, B0k1, aoffB, boffB, acc, b0,b1,b2,b3, gA0, gA1, A0k0, sdoff, kf20, true);
    gphase<1,false, 6>(A0k1, B0k1, aoffB, boffB, acc, b0,b1,b2,b3, gB0, gB1, B0k1, sdoff, kf21, true);
    gphase<0,true ,-1>(A1k0, B1k0, aoffB, boffB, acc, b0,b1,b2,b3, gA0, gA1, A0k1, sdoff, kf21, true);
    gphase<1,false,-1>(A1k0, B1k0, aoffB, boffB, acc, b0,b1,b2,b3, gB0, gB1, B1k0, sdoff, kf30, true);
    gphase<0,true ,-1>(A1k1, B1k1, aoffB, boffB, acc, b0,b1,b2,b3, gA0, gA1, A1k0, sdoff, kf30, true);
    gphase<1,false, 6>(A1k1, B1k1, aoffB, boffB, acc, b0,b1,b2,b3, gB0, gB1, B1k1, sdoff, kf31, true);
  }
  {  // final iteration: tiles nt-2, nt-1; out-of-range stages skipped; drain
    const int t = nt - 2;
    const int kf1 = ((t+1) << 6) + 32;
    gphase<0,true ,-1>(A0k0, B0k0, aoffB, boffB, acc, b0,b1,b2,b3, gA0, gA1, A1k1, sdoff, kf1, true);
    gphase<1,false,-1>(A0k0, B0k0, aoffB, boffB, acc, b0,b1,b2,b3, gB0, gB1, B0k0, sdoff, 0, false);
    gphase<0,true ,-1>(A0k1, B0k1, aoffB, boffB, acc, b0,b1,b2,b3, gA0, gA1, A0k0, sdoff, 0, false);
    gphase<1,false, 0>(A0k1, B0k1, aoffB, boffB, acc, b0,b1,b2,b3, gB0, gB1, B0k1, sdoff, 0, false);
    gphase<0,true ,-1>(A1k0, B1k0, aoffB, boffB, acc, b0,b1,b2,b3, gA0, gA1, A0k1, sdoff, 0, false);
    gphase<1,false,-1>(A1k0, B1k0, aoffB, boffB, acc, b0,b1,b2,b3, gB0, gB1, B1k0, sdoff, 0, false);
    gphase<0,true ,-1>(A1k1, B1k1, aoffB, boffB, acc, b0,b1,b2,b3, gA0, gA1, A1k0, sdoff, 0, false);
    gphase<1,false, 0>(A1k1, B1k1, aoffB, boffB, acc, b0,b1,b2,b3, gB0, gB1, B1k1, sdoff, 0, false);
  }

  if constexpr (EPI == 0) {
    // ---- qkv: wave-local LDS-staged bf16 drain to q/k/v [head][MPAD][64] ----
    __syncthreads();
    char* ep = SMEM + wv * 16384;              // [128 rows][64 cols bf16]
    #pragma unroll
    for (int m = 0; m < 8; ++m) {
      #pragma unroll
      for (int n = 0; n < 4; ++n) {
        const int col = n * 16 + lr;
        const float bv = bias[(int)brow0 + wn * 64 + col];
        #pragma unroll
        for (int e = 0; e < 4; ++e) {
          const int row_l = m * 16 + hi * 4 + e;
          const int byte = row_l * 128 + col * 2;
          *(bf16*)(ep + (byte ^ ((row_l & 7) << 4))) = __float2bfloat16(acc[m][n][e] + bv);
        }
      }
    }
    __syncthreads();
    // wave's 64-col span = one head-d chunk: which/head constant per wave
    const int hchunk = ((int)brow0 + wn * 64) >> 6;      // 0..35
    const int which = hchunk / 12, head = hchunk % 12;
    bf16* dstb = (which == 0) ? ob0 : ((which == 1) ? ob1 : ob2);
    #pragma unroll
    for (int u = 0; u < 16; ++u) {
      const int unit = u * 64 + lane;          // 1024 units of 16 B per wave
      const int row_l = unit >> 3, slot = unit & 7;
      const int byte = row_l * 128 + slot * 16;
      const short8 val = *(const short8*)(ep + (byte ^ ((row_l & 7) << 4)));
      const int grow = (int)arow0 + wm * 128 + row_l;
      if (grow < Mreal)
        *(short8*)&dstb[((size_t)head * MPAD + grow) * 64 + slot * 8] = val;
    }
  } else if constexpr (EPI == 2) {
    // ---- gelu + LDS-staged coalesced bf16 stores (wave-local 8 KB region) ----
    char* ep = SMEM + wv * 8192;               // [64 rows][64 cols bf16]
    #pragma unroll
    for (int h = 0; h < 2; ++h) {
      #pragma unroll
      for (int m2 = 0; m2 < 4; ++m2) {
        #pragma unroll
        for (int n = 0; n < 4; ++n) {
          const int col = n * 16 + lr;
          const float bv = bias[(int)brow0 + wn * 64 + col];
          #pragma unroll
          for (int e = 0; e < 4; ++e) {
            const int row_l = m2 * 16 + hi * 4 + e;
            const float v = gelu_f(acc[h * 4 + m2][n][e] + bv);
            *(bf16*)(ep + row_l * 128 + (((col >> 3) ^ (row_l & 7)) << 4) + ((col & 7) << 1))
                = __float2bfloat16(v);
          }
        }
      }
      #pragma unroll
      for (int p = 0; p < 8; ++p) {
        const int row_l = p * 8 + (lane >> 3);
        const int slot  = lane & 7;
        const short8 val = *(const short8*)(ep + row_l * 128 + ((slot ^ (row_l & 7)) << 4));
        const size_t grow = arow0 + wm * 128 + h * 64 + row_l;
        const int gcol = (int)brow0 + wn * 64 + slot * 8;
        *(short8*)&ob0[grow * 3072 + gcol] = val;
      }
    }
  } else {
    // ---- EPI 3: f32 residual via wave-local LDS staging (256-B rows) ----
    char* ep = SMEM + wv * 16384;              // [64 rows][64 cols f32]
    #pragma unroll
    for (int h = 0; h < 2; ++h) {
      #pragma unroll
      for (int m2 = 0; m2 < 4; ++m2) {
        #pragma unroll
        for (int n = 0; n < 4; ++n) {
          const int col = n * 16 + lr;
          const float bv = bias[(int)brow0 + wn * 64 + col];
          #pragma unroll
          for (int e = 0; e < 4; ++e) {
            const int row_l = m2 * 16 + hi * 4 + e;
            *(float*)(ep + row_l * 256 + col * 4) = acc[h * 4 + m2][n][e] + bv;
          }
        }
      }
      #pragma unroll
      for (int u = 0; u < 16; ++u) {
        const int unit = u * 64 + lane;        // 1024 16-B units per pass
        const int row_l = unit >> 4, ucol = unit & 15;
        const size_t grow = arow0 + wm * 128 + h * 64 + row_l;
        const size_t idx = grow * 768 + (int)brow0 + wn * 64 + ucol * 4;
        const f32x4 sv = *(const f32x4*)(ep + row_l * 256 + ucol * 16);
        const f32x4 fv = *(const f32x4*)&fin[idx];
        f32x4 ov = {sv[0] + fv[0], sv[1] + fv[1], sv[2] + fv[2], sv[3] + fv[3]};
        *(f32x4*)&fout[idx] = ov;
      }
    }
  }
}

// ---------------- fused window attention (r12-proven, untouched) -------------
__global__ __launch_bounds__(512, 2)
void attn_kernel(const bf16* __restrict__ qb, const bf16* __restrict__ kb,
                 const bf16* __restrict__ vb, const float* __restrict__ rph,
                 const float* __restrict__ rpw, bf16* __restrict__ aout) {
  __shared__ __align__(16) char SM[65248];
  bf16* pbh    = (bf16*)SM;
  bf16* pbw    = (bf16*)(SM + 4096);
  bf16* Gh     = (bf16*)(SM + 8192);
  bf16* Gw     = (bf16*)(SM + 23168);
  char* klds   = SM;                    // [200 rows][128 B], XOR-swizzled
  char* vtb    = SM + 25600;            // [64 d][448 B], XOR-swizzled
  bf16* relh_s = (bf16*)(SM + 54272);   // [196][14]
  bf16* relw_s = (bf16*)(SM + 59760);   // [196][14]

  const int bh = blockIdx.x;             // 0..2399
  const int win = bh / 12, head = bh % 12;
  const size_t base = ((size_t)head * MPAD + win * 196) * 64;
  const bf16* Q  = qb + base;
  const bf16* Kp = kb + base;
  const bf16* Vp = vb + base;
  const int tid = threadIdx.x, lane = tid & 63, wv = tid >> 6;   // wv 0..7
  const int lr = lane & 15, hi = lane >> 4;

  for (int i = tid; i < 32 * 64; i += 512) {
    const int r = i >> 6, c = i & 63;
    const bool ok = r < 27;
    pbh[i] = __float2bfloat16(ok ? rph[r * 64 + c] : 0.f);
    pbw[i] = __float2bfloat16(ok ? rpw[r * 64 + c] : 0.f);
  }
  __syncthreads();
  {
    short8 bh00 = *(const short8*)&pbh[(lr) * 64 + hi * 8];
    short8 bh01 = *(const short8*)&pbh[(lr) * 64 + 32 + hi * 8];
    short8 bh10 = *(const short8*)&pbh[(16 + lr) * 64 + hi * 8];
    short8 bh11 = *(const short8*)&pbh[(16 + lr) * 64 + 32 + hi * 8];
    short8 bw00 = *(const short8*)&pbw[(lr) * 64 + hi * 8];
    short8 bw01 = *(const short8*)&pbw[(lr) * 64 + 32 + hi * 8];
    short8 bw10 = *(const short8*)&pbw[(16 + lr) * 64 + hi * 8];
    short8 bw11 = *(const short8*)&pbw[(16 + lr) * 64 + 32 + hi * 8];
    for (int mt = wv; mt < 13; mt += 8) {
      const short8 a0 = *(const short8*)&Q[(mt * 16 + lr) * 64 + hi * 8];
      const short8 a1 = *(const short8*)&Q[(mt * 16 + lr) * 64 + 32 + hi * 8];
      f32x4 g0 = {}, g1 = {}, g2 = {}, g3 = {};
      g0 = mfma16x16x32(a0, bh00, g0); g0 = mfma16x16x32(a1, bh01, g0);
      g1 = mfma16x16x32(a0, bh10, g1); g1 = mfma16x16x32(a1, bh11, g1);
      g2 = mfma16x16x32(a0, bw00, g2); g2 = mfma16x16x32(a1, bw01, g2);
      g3 = mfma16x16x32(a0, bw10, g3); g3 = mfma16x16x32(a1, bw11, g3);
      #pragma unroll
      for (int e = 0; e < 4; ++e) {
        const int row = mt * 16 + hi * 4 + e;
        Gh[row * 36 + lr]      = __float2bfloat16(g0[e]);
        Gh[row * 36 + 16 + lr] = __float2bfloat16(g1[e]);
        Gw[row * 36 + lr]      = __float2bfloat16(g2[e]);
        Gw[row * 36 + 16 + lr] = __float2bfloat16(g3[e]);
      }
    }
  }
  __syncthreads();
  bf16 ghr[6], gwr[6];
  #pragma unroll
  for (int t = 0; t < 6; ++t) {
    const int i = tid + t * 512;
    if (i < 196 * 14) {
      const int q = i / 14, kk = i - (i / 14) * 14;
      const int rh = q / 14 - kk + 13;
      const int rw2 = q - (q / 14) * 14 - kk + 13;
      ghr[t] = Gh[q * 36 + rh];
      gwr[t] = Gw[q * 36 + rw2];
    }
  }
  __syncthreads();
  #pragma unroll
  for (int t = 0; t < 6; ++t) {
    const int i = tid + t * 512;
    if (i < 196 * 14) { relh_s[i] = ghr[t]; relw_s[i] = gwr[t]; }
  }
  for (int c = wv; c < 25; c += 8) {
    const int row = c * 8 + (lane >> 3);
    const int ch  = (lane & 7) ^ (row & 7);
    gload_lds16(Kp + row * 64 + ch * 8, klds + c * 1024);
  }
  for (int i = tid; i < 196 * 8; i += 512) {
    const int key = i >> 3, dg = (i & 7) * 8;
    const short8 v = *(const short8*)&Vp[key * 64 + dg];
    #pragma unroll
    for (int j = 0; j < 8; ++j) {
      const int idx = (dg + j) * 448 + key * 2;
      *(bf16*)(vtb + (idx ^ (j << 4))) = ((const bf16*)&v)[j];
    }
  }
  for (int i = tid; i < 64 * 28; i += 512) {
    const int d = i / 28, key = 196 + i - (i / 28) * 28;
    const int idx = d * 448 + key * 2;
    *(bf16*)(vtb + (idx ^ ((d & 7) << 4))) = __float2bfloat16(0.f);
  }
  __syncthreads();

  for (int qt = wv; qt < 13; qt += 8) {
    const int q = qt * 16 + lr;
    const int qc = q < 196 ? q : 195;
    const short8 bq0 = *(const short8*)&Q[(qt * 16 + lr) * 64 + hi * 8];
    const short8 bq1 = *(const short8*)&Q[(qt * 16 + lr) * 64 + 32 + hi * 8];
    f32x4 s[13];
    __builtin_amdgcn_s_setprio(1);
    #pragma unroll
    for (int nt = 0; nt < 13; ++nt) {
      const int key = nt * 16 + lr;
      const char* kr = klds + key * 128;
      const short8 ka0 = *(const short8*)(kr + (((hi) ^ (key & 7)) << 4));
      const short8 ka1 = *(const short8*)(kr + (((hi + 4) ^ (key & 7)) << 4));
      f32x4 z = {};
      z = mfma16x16x32(ka0, bq0, z);
      z = mfma16x16x32(ka1, bq1, z);
      s[nt] = z;
    }
    __builtin_amdgcn_s_setprio(0);
    float mx = -3.0e38f;
    #pragma unroll
    for (int nt = 0; nt < 13; ++nt) {
      #pragma unroll
      for (int e = 0; e < 4; ++e) {
        const int key = nt * 16 + hi * 4 + e;
        const int kh = key / 14, kw = key - kh * 14;
        float v = s[nt][e] * 0.125f + __bfloat162float(relh_s[qc * 14 + kh])
                                    + __bfloat162float(relw_s[qc * 14 + kw]);
        v = (key < 196) ? v : -3.0e38f;
        s[nt][e] = v;
        mx = fmaxf(mx, v);
      }
    }
    mx = fmaxf(mx, __shfl_xor(mx, 16));
    mx = fmaxf(mx, __shfl_xor(mx, 32));
    float sm = 0.f;
    uint32_t pk0[14], pk1[14];
    #pragma unroll
    for (int nt = 0; nt < 13; ++nt) {
      const float p0 = __expf(s[nt][0] - mx);
      const float p1 = __expf(s[nt][1] - mx);
      const float p2 = __expf(s[nt][2] - mx);
      const float p3 = __expf(s[nt][3] - mx);
      sm += (p0 + p1) + (p2 + p3);
      pk0[nt] = cvtpk(p0, p1);
      pk1[nt] = cvtpk(p2, p3);
    }
    pk0[13] = 0u; pk1[13] = 0u;
    sm += __shfl_xor(sm, 16);
    sm += __shfl_xor(sm, 32);
    const float rinv = 1.f / sm;
    f32x4 o[4] = {};
    #pragma unroll
    for (int kk = 0; kk < 7; ++kk) {
      const uint32_t x0 = pk0[2 * kk],     x1 = pk1[2 * kk];
      const uint32_t y0 = pk0[2 * kk + 1], y1 = pk1[2 * kk + 1];
      const uint32_t s0 = (hi < 2) ? y0 : x0, s1 = (hi < 2) ? y1 : x1;
      const uint32_t t0 = __shfl_xor(s0, 32), t1 = __shfl_xor(s1, 32);
      const uint32_t o0 = (hi < 2) ? x0 : y0, o1 = (hi < 2) ? x1 : y1;
      const bool sendOwn = (hi == 1) || (hi == 2);
      const uint32_t u0 = sendOwn ? o0 : t0, u1 = sendOwn ? o1 : t1;
      const uint32_t r0 = __shfl_xor(u0, 16), r1 = __shfl_xor(u1, 16);
      union { uint32_t u[4]; short8 v; } pf;
      pf.u[0] = (hi == 0) ? x0 : ((hi == 2) ? t0 : r0);
      pf.u[1] = (hi == 0) ? x1 : ((hi == 2) ? t1 : r1);
      pf.u[2] = (hi == 3) ? y0 : ((hi == 1) ? t0 : r0);
      pf.u[3] = (hi == 3) ? y1 : ((hi == 1) ? t1 : r1);
      __builtin_amdgcn_s_setprio(1);
      #pragma unroll
      for (int n2 = 0; n2 < 4; ++n2) {
        const int d = n2 * 16 + lr;
        const int idx = d * 448 + (kk * 32 + hi * 8) * 2;
        const short8 va = *(const short8*)(vtb + (idx ^ ((lr & 7) << 4)));
        o[n2] = mfma16x16x32(va, pf.v, o[n2]);
      }
      __builtin_amdgcn_s_setprio(0);
    }
    if (q < 196) {
      bf16* orow = aout + ((size_t)head * MPAD + win * 196 + q) * 64;
      #pragma unroll
      for (int n2 = 0; n2 < 4; ++n2) {
        uint32_t d0 = cvtpk(o[n2][0] * rinv, o[n2][1] * rinv);
        uint32_t d1 = cvtpk(o[n2][2] * rinv, o[n2][3] * rinv);
        uint32_t* dst = (uint32_t*)&orow[n2 * 16 + hi * 4];
        dst[0] = d0; dst[1] = d1;
      }
    }
  }
}

// ---------------- host ----------------
extern "C" void kernel_launch(void* const* d_in, const int* in_sizes, int n_in,
                              void* d_out, int out_size, void* d_ws, size_t ws_size,
                              hipStream_t stream) {
  (void)in_sizes; (void)n_in; (void)out_size; (void)ws_size;
  const float* x      = (const float*)d_in[0];
  const float* ln1_g  = (const float*)d_in[1];
  const float* ln1_b  = (const float*)d_in[2];
  const float* qkv_w  = (const float*)d_in[3];
  const float* qkv_b  = (const float*)d_in[4];
  const float* proj_w = (const float*)d_in[5];
  const float* proj_b = (const float*)d_in[6];
  const float* rph    = (const float*)d_in[7];
  const float* rpw    = (const float*)d_in[8];
  const float* ln2_g  = (const float*)d_in[9];
  const float* ln2_b  = (const float*)d_in[10];
  const float* w1     = (const float*)d_in[11];
  const float* b1v    = (const float*)d_in[12];
  const float* w2     = (const float*)d_in[13];
  const float* b2v    = (const float*)d_in[14];
  float* outp = (float*)d_out;   // also serves as x1 (written by proj epilogue)

  char* ws = (char*)d_ws;
  size_t off = 0;
  auto alloc = [&](size_t bytes) { char* p = ws + off; off += (bytes + 255) & ~(size_t)255; return p; };
  bf16* qkv_wt  = (bf16*)alloc((size_t)2304 * 768 * 2);
  bf16* proj_wt = (bf16*)alloc((size_t)768 * 768 * 2);
  bf16* w1t     = (bf16*)alloc((size_t)3072 * 768 * 2);
  bf16* w2t     = (bf16*)alloc((size_t)768 * 3072 * 2);
  const size_t szB1 = (size_t)MPAD * 768 * 2;
  const size_t szB2 = (size_t)TOK2 * 768 * 2;
  char* regB = alloc(szB1 > szB2 ? szB1 : szB2);
  const size_t szQKV = (size_t)3 * 12 * MPAD * 64 * 2;
  const size_t szH   = (size_t)TOK2 * 3072 * 2;
  char* regC = alloc(szQKV > szH ? szQKV : szH);

  bf16* xnwin   = (bf16*)regB;
  bf16* attnout = (bf16*)regB;
  bf16* xn2     = (bf16*)regB;
  bf16* qbuf    = (bf16*)regC;                       // [12][MPAD][64]
  bf16* kbuf    = qbuf + (size_t)12 * MPAD * 64;
  bf16* vbuf    = kbuf + (size_t)12 * MPAD * 64;
  bf16* hbuf    = (bf16*)regC;

  transpose_cast<<<dim3(2304 / 32, 768 / 32), 256, 0, stream>>>(qkv_w, qkv_wt, 768, 2304);
  transpose_cast<<<dim3(768 / 32, 768 / 32), 256, 0, stream>>>(proj_w, proj_wt, 768, 768);
  transpose_cast<<<dim3(3072 / 32, 768 / 32), 256, 0, stream>>>(w1, w1t, 768, 3072);
  transpose_cast<<<dim3(768 / 32, 3072 / 32), 256, 0, stream>>>(w2, w2t, 3072, 768);

  ln1_partition<<<dim3(MROWS / 4), 256, 0, stream>>>(x, ln1_g, ln1_b, xnwin);

  // qkv on the 8-phase 256^2 kernel (M padded to 39424)
  gemm256<0, 768><<<dim3(2304 / 256, MPAD / 256), 512, 0, stream>>>(
      xnwin, qkv_wt, qkv_b, MROWS, nullptr, nullptr, qbuf, kbuf, vbuf);

  attn_kernel<<<dim3(2400), 512, 0, stream>>>(qbuf, kbuf, vbuf, rph, rpw, attnout);

  gemm_bf16<1><<<dim3(768 / 128, MPAD / 128), 256, 0, stream>>>(
      attnout, proj_wt, proj_b, 768, MROWS, x, outp, nullptr, nullptr, nullptr);

  ln2_kernel<<<dim3(TOK2 / 4), 256, 0, stream>>>(outp, ln2_g, ln2_b, xn2);

  // MLP on the 8-phase 256^2 kernel
  gemm256<2, 768><<<dim3(3072 / 256, TOK2 / 256), 512, 0, stream>>>(
      xn2, w1t, b1v, TOK2, nullptr, nullptr, hbuf, nullptr, nullptr);
  gemm256<3, 3072><<<dim3(768 / 256, TOK2 / 256), 512, 0, stream>>>(
      hbuf, w2t, b2v, TOK2, outp, outp, nullptr, nullptr, nullptr);
}